// Round 4
// baseline (6492.453 us; speedup 1.0000x reference)
//
#include <hip/hip_runtime.h>
#include <math.h>
#include <type_traits>

typedef unsigned short ushort_t;

__device__ __forceinline__ float lrelu(float x) { return x >= 0.f ? x : 0.01f * x; }

// bf16 (raw ushort) <-> f32, RNE rounding, no library dependency.
__device__ __forceinline__ float bu2f(ushort_t u) {
    unsigned int x = ((unsigned int)u) << 16;
    float f; __builtin_memcpy(&f, &x, 4); return f;
}
__device__ __forceinline__ ushort_t f2bu(float f) {
    unsigned int x; __builtin_memcpy(&x, &f, 4);
    unsigned int r = (x + 0x7FFFu + ((x >> 16) & 1u)) >> 16;
    return (ushort_t)r;
}

// Generic 3x3 conv, pad=1, stride 1 or 2, NHWC, fused bias + LeakyReLU.
// Input f32 or bf16(ushort); output bf16. Each thread: 4-wide Cout tile.
template <typename Tin>
__global__ __launch_bounds__(256) void conv3x3_c4_kernel(
    const Tin* __restrict__ in, const float* __restrict__ wgt,
    const float* __restrict__ bias, ushort_t* __restrict__ out,
    int B, int Hin, int Win, int Cin, int Cout, int Ho, int Wo, int stride)
{
    const int CoT = Cout >> 2;
    int idx = blockIdx.x * 256 + threadIdx.x;
    int total = B * Ho * Wo * CoT;
    if (idx >= total) return;
    int cg = idx % CoT;
    int t  = idx / CoT;
    int wo = t % Wo; t /= Wo;
    int ho = t % Ho;
    int b  = t / Ho;
    int co = cg << 2;

    float4 bv = *reinterpret_cast<const float4*>(bias + co);
    float a0 = bv.x, a1 = bv.y, a2 = bv.z, a3 = bv.w;

    const int hb = ho * stride - 1;
    const int wb = wo * stride - 1;
    const bool cin4 = (Cin & 3) == 0;

    for (int dy = 0; dy < 3; ++dy) {
        int hi = hb + dy;
        if ((unsigned)hi >= (unsigned)Hin) continue;
        for (int dx = 0; dx < 3; ++dx) {
            int wi = wb + dx;
            if ((unsigned)wi >= (unsigned)Win) continue;
            const Tin* ip = in + ((b * Hin + hi) * Win + wi) * Cin;
            const float* wp = wgt + (dy * 3 + dx) * Cin * Cout + co;
            if (cin4) {
                for (int ci = 0; ci < Cin; ci += 4) {
                    float i0, i1, i2, i3;
                    if constexpr (std::is_same<Tin, float>::value) {
                        float4 iv = *reinterpret_cast<const float4*>(ip + ci);
                        i0 = iv.x; i1 = iv.y; i2 = iv.z; i3 = iv.w;
                    } else {
                        ushort4 uv = *reinterpret_cast<const ushort4*>(ip + ci);
                        i0 = bu2f(uv.x); i1 = bu2f(uv.y); i2 = bu2f(uv.z); i3 = bu2f(uv.w);
                    }
                    float4 w0 = *reinterpret_cast<const float4*>(wp + (ci + 0) * Cout);
                    float4 w1 = *reinterpret_cast<const float4*>(wp + (ci + 1) * Cout);
                    float4 w2 = *reinterpret_cast<const float4*>(wp + (ci + 2) * Cout);
                    float4 w3 = *reinterpret_cast<const float4*>(wp + (ci + 3) * Cout);
                    a0 = fmaf(i0, w0.x, a0); a1 = fmaf(i0, w0.y, a1); a2 = fmaf(i0, w0.z, a2); a3 = fmaf(i0, w0.w, a3);
                    a0 = fmaf(i1, w1.x, a0); a1 = fmaf(i1, w1.y, a1); a2 = fmaf(i1, w1.z, a2); a3 = fmaf(i1, w1.w, a3);
                    a0 = fmaf(i2, w2.x, a0); a1 = fmaf(i2, w2.y, a1); a2 = fmaf(i2, w2.z, a2); a3 = fmaf(i2, w2.w, a3);
                    a0 = fmaf(i3, w3.x, a0); a1 = fmaf(i3, w3.y, a1); a2 = fmaf(i3, w3.z, a2); a3 = fmaf(i3, w3.w, a3);
                }
            } else {
                for (int ci = 0; ci < Cin; ++ci) {
                    float ivs;
                    if constexpr (std::is_same<Tin, float>::value) ivs = ip[ci];
                    else ivs = bu2f(ip[ci]);
                    float4 wv = *reinterpret_cast<const float4*>(wp + ci * Cout);
                    a0 = fmaf(ivs, wv.x, a0); a1 = fmaf(ivs, wv.y, a1);
                    a2 = fmaf(ivs, wv.z, a2); a3 = fmaf(ivs, wv.w, a3);
                }
            }
        }
    }
    ushort4 res;
    res.x = f2bu(lrelu(a0)); res.y = f2bu(lrelu(a1));
    res.z = f2bu(lrelu(a2)); res.w = f2bu(lrelu(a3));
    *reinterpret_cast<ushort4*>(out + ((b * Ho + ho) * Wo + wo) * Cout + co) = res;
}

// Transposed conv: k=3, lhs_dilation=2, pad (1,2) -> output doubles H,W.
// bf16 in/skip/out. Fused bias + LeakyReLU + skip add (skip may alias out:
// same-index read-then-write by the same thread).
__global__ __launch_bounds__(256) void tconv3x3_c4_kernel(
    const ushort_t* __restrict__ in, const float* __restrict__ wgt,
    const float* __restrict__ bias, const ushort_t* __restrict__ skip,
    ushort_t* __restrict__ out,
    int B, int Hin, int Win, int Cin, int Cout)
{
    const int Ho = Hin * 2, Wo = Win * 2;
    const int CoT = Cout >> 2;
    int idx = blockIdx.x * 256 + threadIdx.x;
    int total = B * Ho * Wo * CoT;
    if (idx >= total) return;
    int cg = idx % CoT;
    int t  = idx / CoT;
    int wo = t % Wo; t /= Wo;
    int ho = t % Ho;
    int b  = t / Ho;
    int co = cg << 2;

    float4 bv = *reinterpret_cast<const float4*>(bias + co);
    float a0 = bv.x, a1 = bv.y, a2 = bv.z, a3 = bv.w;

    for (int dy = 0; dy < 3; ++dy) {
        int d = ho + dy - 1;               // dilated (pre-pad) coord; pad_lo = 1
        if (d < 0 || d > 2 * Hin - 2 || (d & 1)) continue;
        int hi = d >> 1;
        for (int dx = 0; dx < 3; ++dx) {
            int e = wo + dx - 1;
            if (e < 0 || e > 2 * Win - 2 || (e & 1)) continue;
            int wi = e >> 1;
            const ushort_t* ip = in + ((b * Hin + hi) * Win + wi) * Cin;
            const float* wp = wgt + (dy * 3 + dx) * Cin * Cout + co;
            for (int ci = 0; ci < Cin; ci += 4) {
                ushort4 uv = *reinterpret_cast<const ushort4*>(ip + ci);
                float i0 = bu2f(uv.x), i1 = bu2f(uv.y), i2 = bu2f(uv.z), i3 = bu2f(uv.w);
                float4 w0 = *reinterpret_cast<const float4*>(wp + (ci + 0) * Cout);
                float4 w1 = *reinterpret_cast<const float4*>(wp + (ci + 1) * Cout);
                float4 w2 = *reinterpret_cast<const float4*>(wp + (ci + 2) * Cout);
                float4 w3 = *reinterpret_cast<const float4*>(wp + (ci + 3) * Cout);
                a0 = fmaf(i0, w0.x, a0); a1 = fmaf(i0, w0.y, a1); a2 = fmaf(i0, w0.z, a2); a3 = fmaf(i0, w0.w, a3);
                a0 = fmaf(i1, w1.x, a0); a1 = fmaf(i1, w1.y, a1); a2 = fmaf(i1, w1.z, a2); a3 = fmaf(i1, w1.w, a3);
                a0 = fmaf(i2, w2.x, a0); a1 = fmaf(i2, w2.y, a1); a2 = fmaf(i2, w2.z, a2); a3 = fmaf(i2, w2.w, a3);
                a0 = fmaf(i3, w3.x, a0); a1 = fmaf(i3, w3.y, a1); a2 = fmaf(i3, w3.z, a2); a3 = fmaf(i3, w3.w, a3);
            }
        }
    }
    int o = ((b * Ho + ho) * Wo + wo) * Cout + co;
    ushort4 sv = *reinterpret_cast<const ushort4*>(skip + o);
    ushort4 res;
    res.x = f2bu(lrelu(a0) + bu2f(sv.x)); res.y = f2bu(lrelu(a1) + bu2f(sv.y));
    res.z = f2bu(lrelu(a2) + bu2f(sv.z)); res.w = f2bu(lrelu(a3) + bu2f(sv.w));
    *reinterpret_cast<ushort4*>(out + o) = res;
}

// Fused final stage: dec0 (3x3 conv 16->16, bias+lrelu) + 1x1 conv 16->1
// + triangular mask + softplus on diagonal. bf16 in, f32 out.
__global__ __launch_bounds__(256) void dec0_out_mask_kernel(
    const ushort_t* __restrict__ in,     // up0 [B,N,N,16] bf16
    const float* __restrict__ w_dec,     // [3,3,16,16]
    const float* __restrict__ b_dec,     // [16]
    const float* __restrict__ w_out,     // [16]
    const float* __restrict__ b_out,     // [1]
    float* __restrict__ out, int B, int N)
{
    int idx = blockIdx.x * 256 + threadIdx.x;
    int total = B * N * N;
    if (idx >= total) return;
    int col = idx % N;
    int t   = idx / N;
    int row = t % N;
    int b   = t / N;

    float acc[16];
    #pragma unroll
    for (int c = 0; c < 16; ++c) acc[c] = b_dec[c];

    for (int dy = 0; dy < 3; ++dy) {
        int hi = row + dy - 1;
        if ((unsigned)hi >= (unsigned)N) continue;
        for (int dx = 0; dx < 3; ++dx) {
            int wi = col + dx - 1;
            if ((unsigned)wi >= (unsigned)N) continue;
            const ushort_t* ip = in + (((long)b * N + hi) * N + wi) * 16;
            const float* wp = w_dec + (dy * 3 + dx) * 256;
            #pragma unroll
            for (int c4 = 0; c4 < 4; ++c4) {
                ushort4 uv = *reinterpret_cast<const ushort4*>(ip + c4 * 4);
                float iv[4] = { bu2f(uv.x), bu2f(uv.y), bu2f(uv.z), bu2f(uv.w) };
                #pragma unroll
                for (int k = 0; k < 4; ++k) {
                    int ci = c4 * 4 + k;
                    const float* wr = wp + ci * 16;
                    #pragma unroll
                    for (int c = 0; c < 16; c += 4) {
                        float4 wv = *reinterpret_cast<const float4*>(wr + c);
                        acc[c + 0] = fmaf(iv[k], wv.x, acc[c + 0]);
                        acc[c + 1] = fmaf(iv[k], wv.y, acc[c + 1]);
                        acc[c + 2] = fmaf(iv[k], wv.z, acc[c + 2]);
                        acc[c + 3] = fmaf(iv[k], wv.w, acc[c + 3]);
                    }
                }
            }
        }
    }

    float interim = b_out[0];
    #pragma unroll
    for (int c = 0; c < 16; ++c) interim = fmaf(lrelu(acc[c]), w_out[c], interim);

    float v;
    if (row < col) {
        v = 0.f;
    } else if (row == col) {
        v = fmaxf(interim, 0.f) + log1pf(expf(-fabsf(interim)));  // stable softplus
    } else {
        v = interim;
    }
    out[idx] = v;
}

extern "C" void kernel_launch(void* const* d_in, const int* in_sizes, int n_in,
                              void* d_out, int out_size, void* d_ws, size_t ws_size,
                              hipStream_t stream)
{
    const float* x      = (const float*)d_in[0];
    const float* w_enc1 = (const float*)d_in[1];  const float* b_enc1 = (const float*)d_in[2];
    const float* w_down1= (const float*)d_in[3];  const float* b_down1= (const float*)d_in[4];
    const float* w_enc2 = (const float*)d_in[5];  const float* b_enc2 = (const float*)d_in[6];
    const float* w_down2= (const float*)d_in[7];  const float* b_down2= (const float*)d_in[8];
    const float* w_enc3 = (const float*)d_in[9];  const float* b_enc3 = (const float*)d_in[10];
    const float* w_bn   = (const float*)d_in[11]; const float* b_bn   = (const float*)d_in[12];
    const float* w_up2  = (const float*)d_in[13]; const float* b_up2  = (const float*)d_in[14];
    const float* w_dec2 = (const float*)d_in[15]; const float* b_dec2 = (const float*)d_in[16];
    const float* w_up1  = (const float*)d_in[17]; const float* b_up1  = (const float*)d_in[18];
    const float* w_dec1 = (const float*)d_in[19]; const float* b_dec1 = (const float*)d_in[20];
    const float* w_up0  = (const float*)d_in[21]; const float* b_up0  = (const float*)d_in[22];
    const float* w_dec0 = (const float*)d_in[23]; const float* b_dec0 = (const float*)d_in[24];
    const float* w_out  = (const float*)d_in[25]; const float* b_out  = (const float*)d_in[26];

    // Workspace layout in bf16 elements. Total 88,080,384 elems = 168 MB.
    ushort_t* ws   = (ushort_t*)d_ws;
    ushort_t* E1   = ws;                 // [8,512,512,16] enc1, later up0 (in-place)
    ushort_t* T256 = E1   + 33554432;    // [8,256,256,32] down1, later up1
    ushort_t* E2   = T256 + 16777216;    // [8,256,256,32] enc2, later dec1
    ushort_t* T128 = E2   + 16777216;    // [8,128,128,64] down2, later up2
    ushort_t* E3   = T128 + 8388608;     // [8,128,128,64] enc3, later dec2
    ushort_t* T64  = E3   + 8388608;     // [8, 64, 64,128] bneck

    const size_t needed = 88080384ull * sizeof(ushort_t);
    if (ws_size < needed) {
        // Workspace too small: fail loudly-but-safely (absmax == ref max, no fault).
        hipMemsetAsync(d_out, 0, (size_t)out_size * sizeof(float), stream);
        return;
    }

    const int B = 8;
    auto convf = [&](const float* in, const float* w, const float* bias, ushort_t* out,
                     int Hin, int Cin, int Cout, int stride) {
        int Ho = (stride == 2) ? Hin / 2 : Hin;
        int total = B * Ho * Ho * (Cout >> 2);
        hipLaunchKernelGGL(conv3x3_c4_kernel<float>, dim3((total + 255) / 256), dim3(256), 0, stream,
                           in, w, bias, out, B, Hin, Hin, Cin, Cout, Ho, Ho, stride);
    };
    auto convb = [&](const ushort_t* in, const float* w, const float* bias, ushort_t* out,
                     int Hin, int Cin, int Cout, int stride) {
        int Ho = (stride == 2) ? Hin / 2 : Hin;
        int total = B * Ho * Ho * (Cout >> 2);
        hipLaunchKernelGGL(conv3x3_c4_kernel<ushort_t>, dim3((total + 255) / 256), dim3(256), 0, stream,
                           in, w, bias, out, B, Hin, Hin, Cin, Cout, Ho, Ho, stride);
    };
    auto tconv = [&](const ushort_t* in, const float* w, const float* bias, const ushort_t* skip,
                     ushort_t* out, int Hin, int Cin, int Cout) {
        int Ho = Hin * 2;
        int total = B * Ho * Ho * (Cout >> 2);
        hipLaunchKernelGGL(tconv3x3_c4_kernel, dim3((total + 255) / 256), dim3(256), 0, stream,
                           in, w, bias, skip, out, B, Hin, Hin, Cin, Cout);
    };

    convf(x,    w_enc1,  b_enc1,  E1,   512,   1,  16, 1);    // enc1
    convb(E1,   w_down1, b_down1, T256, 512,  16,  32, 2);    // down1
    convb(T256, w_enc2,  b_enc2,  E2,   256,  32,  32, 1);    // enc2
    convb(E2,   w_down2, b_down2, T128, 256,  32,  64, 2);    // down2
    convb(T128, w_enc3,  b_enc3,  E3,   128,  64,  64, 1);    // enc3
    convb(E3,   w_bn,    b_bn,    T64,  128,  64, 128, 2);    // bneck
    tconv(T64,  w_up2,   b_up2,   E3,   T128,  64, 128,  64); // up2 = lrelu(tconv)+enc3
    convb(T128, w_dec2,  b_dec2,  E3,   128,  64,  64, 1);    // dec2 (E3 dead -> reuse)
    tconv(E3,   w_up1,   b_up1,   E2,   T256, 128,  64,  32); // up1 = +enc2
    convb(T256, w_dec1,  b_dec1,  E2,   256,  32,  32, 1);    // dec1 (E2 dead -> reuse)
    tconv(E2,   w_up0,   b_up0,   E1,   E1,   256,  32,  16); // up0 = +enc1 (in-place)

    int total = B * 512 * 512;
    hipLaunchKernelGGL(dec0_out_mask_kernel, dim3((total + 255) / 256), dim3(256), 0, stream,
                       E1, w_dec0, b_dec0, w_out, b_out, (float*)d_out, B, 512);
}

// Round 5
// 2921.222 us; speedup vs baseline: 2.2225x; 2.2225x over previous
//
#include <hip/hip_runtime.h>
#include <math.h>
#include <type_traits>

typedef unsigned short ushort_t;

__device__ __forceinline__ float lrelu(float x) { return x >= 0.f ? x : 0.01f * x; }

// bf16 (raw ushort) <-> f32, RNE rounding.
__device__ __forceinline__ float bu2f(ushort_t u) {
    unsigned int x = ((unsigned int)u) << 16;
    float f; __builtin_memcpy(&f, &x, 4); return f;
}
__device__ __forceinline__ ushort_t f2bu(float f) {
    unsigned int x; __builtin_memcpy(&x, &f, 4);
    unsigned int r = (x + 0x7FFFu + ((x >> 16) & 1u)) >> 16;
    return (ushort_t)r;
}

// 3x3 conv, pad=1, NHWC, fused bias+LeakyReLU, bf16 out.
// Register-blocked: each thread computes 4 consecutive-w pixels x 4 Cout.
// Per dy/ci4: NC input loads + 12 weight loads -> 192 FMAs (ILP + amortization).
template <typename Tin, int STRIDE>
__global__ __launch_bounds__(256) void conv3x3_px4_kernel(
    const Tin* __restrict__ in, const float* __restrict__ wgt,
    const float* __restrict__ bias, ushort_t* __restrict__ out,
    int B, int Hin, int Win, int Cin, int Cout, int Ho, int Wo)
{
    constexpr int NC = 3 * STRIDE + 3;   // input columns touched by 4 outputs
    const int CoT = Cout >> 2;
    const int Wo4 = Wo >> 2;
    int idx = blockIdx.x * 256 + threadIdx.x;
    int total = B * Ho * Wo4 * CoT;
    if (idx >= total) return;
    int cg = idx % CoT; int t = idx / CoT;
    int wg = t % Wo4;   t /= Wo4;
    int ho = t % Ho;    int b = t / Ho;
    int co = cg << 2;
    int wo0 = wg << 2;

    float4 bv = *reinterpret_cast<const float4*>(bias + co);
    float acc[4][4];
    #pragma unroll
    for (int px = 0; px < 4; ++px) {
        acc[px][0] = bv.x; acc[px][1] = bv.y; acc[px][2] = bv.z; acc[px][3] = bv.w;
    }

    const int hb  = ho * STRIDE - 1;
    const int wb0 = wo0 * STRIDE - 1;

    if ((Cin & 3) == 0) {
        for (int dy = 0; dy < 3; ++dy) {
            int hi = hb + dy;
            if ((unsigned)hi >= (unsigned)Hin) continue;
            const Tin* rowp = in + ((long)(b * Hin + hi) * Win) * Cin;
            for (int ci = 0; ci < Cin; ci += 4) {
                float iv[NC][4];
                #pragma unroll
                for (int c = 0; c < NC; ++c) {
                    int wi = wb0 + c;
                    if ((unsigned)wi < (unsigned)Win) {
                        if constexpr (std::is_same<Tin, float>::value) {
                            float4 v = *reinterpret_cast<const float4*>(rowp + (long)wi * Cin + ci);
                            iv[c][0] = v.x; iv[c][1] = v.y; iv[c][2] = v.z; iv[c][3] = v.w;
                        } else {
                            ushort4 v = *reinterpret_cast<const ushort4*>(rowp + (long)wi * Cin + ci);
                            iv[c][0] = bu2f(v.x); iv[c][1] = bu2f(v.y);
                            iv[c][2] = bu2f(v.z); iv[c][3] = bu2f(v.w);
                        }
                    } else {
                        iv[c][0] = iv[c][1] = iv[c][2] = iv[c][3] = 0.f;
                    }
                }
                #pragma unroll
                for (int dx = 0; dx < 3; ++dx) {
                    const float* wp = wgt + ((long)(dy * 3 + dx) * Cin + ci) * Cout + co;
                    float4 w0 = *reinterpret_cast<const float4*>(wp);
                    float4 w1 = *reinterpret_cast<const float4*>(wp + Cout);
                    float4 w2 = *reinterpret_cast<const float4*>(wp + 2 * Cout);
                    float4 w3 = *reinterpret_cast<const float4*>(wp + 3 * Cout);
                    #pragma unroll
                    for (int px = 0; px < 4; ++px) {
                        const float* v = iv[px * STRIDE + dx];
                        acc[px][0] = fmaf(v[0], w0.x, acc[px][0]); acc[px][1] = fmaf(v[0], w0.y, acc[px][1]);
                        acc[px][2] = fmaf(v[0], w0.z, acc[px][2]); acc[px][3] = fmaf(v[0], w0.w, acc[px][3]);
                        acc[px][0] = fmaf(v[1], w1.x, acc[px][0]); acc[px][1] = fmaf(v[1], w1.y, acc[px][1]);
                        acc[px][2] = fmaf(v[1], w1.z, acc[px][2]); acc[px][3] = fmaf(v[1], w1.w, acc[px][3]);
                        acc[px][0] = fmaf(v[2], w2.x, acc[px][0]); acc[px][1] = fmaf(v[2], w2.y, acc[px][1]);
                        acc[px][2] = fmaf(v[2], w2.z, acc[px][2]); acc[px][3] = fmaf(v[2], w2.w, acc[px][3]);
                        acc[px][0] = fmaf(v[3], w3.x, acc[px][0]); acc[px][1] = fmaf(v[3], w3.y, acc[px][1]);
                        acc[px][2] = fmaf(v[3], w3.z, acc[px][2]); acc[px][3] = fmaf(v[3], w3.w, acc[px][3]);
                    }
                }
            }
        }
    } else {  // Cin == 1 (enc1)
        for (int dy = 0; dy < 3; ++dy) {
            int hi = hb + dy;
            if ((unsigned)hi >= (unsigned)Hin) continue;
            const Tin* rowp = in + (long)(b * Hin + hi) * Win;
            float iv[NC];
            #pragma unroll
            for (int c = 0; c < NC; ++c) {
                int wi = wb0 + c;
                float v = 0.f;
                if ((unsigned)wi < (unsigned)Win) {
                    if constexpr (std::is_same<Tin, float>::value) v = rowp[wi];
                    else v = bu2f(rowp[wi]);
                }
                iv[c] = v;
            }
            #pragma unroll
            for (int dx = 0; dx < 3; ++dx) {
                const float* wp = wgt + (long)(dy * 3 + dx) * Cout + co;
                float4 w = *reinterpret_cast<const float4*>(wp);
                #pragma unroll
                for (int px = 0; px < 4; ++px) {
                    float v = iv[px * STRIDE + dx];
                    acc[px][0] = fmaf(v, w.x, acc[px][0]); acc[px][1] = fmaf(v, w.y, acc[px][1]);
                    acc[px][2] = fmaf(v, w.z, acc[px][2]); acc[px][3] = fmaf(v, w.w, acc[px][3]);
                }
            }
        }
    }

    #pragma unroll
    for (int px = 0; px < 4; ++px) {
        ushort4 res;
        res.x = f2bu(lrelu(acc[px][0])); res.y = f2bu(lrelu(acc[px][1]));
        res.z = f2bu(lrelu(acc[px][2])); res.w = f2bu(lrelu(acc[px][3]));
        *reinterpret_cast<ushort4*>(out + ((long)(b * Ho + ho) * Wo + wo0 + px) * Cout + co) = res;
    }
}

// Transposed conv k=3, lhs_dilation=2, pad(1,2): output doubles H,W.
// Register-blocked: each thread computes a 2x4 output block x 4 Cout from a
// 2x3 input patch. Tap algebra: output(2hi+py, 2wi+px): py=0 -> dy=1 (row hi);
// py=1 -> dy=0 (row hi), dy=2 (row hi+1). Each tap (dy,dx) feeds exactly 2 of
// the 8 outputs. Fused bias+lrelu+skip add (skip may alias out; same thread rw).
__global__ __launch_bounds__(256) void tconv3x3_q8_kernel(
    const ushort_t* __restrict__ in, const float* __restrict__ wgt,
    const float* __restrict__ bias, const ushort_t* __restrict__ skip,
    ushort_t* __restrict__ out,
    int B, int Hin, int Win, int Cin, int Cout)
{
    const int Ho = Hin * 2, Wo = Win * 2;
    const int CoT = Cout >> 2;
    const int Wg = Win >> 1;            // 4 output cols per thread = 2 input cols
    int idx = blockIdx.x * 256 + threadIdx.x;
    int total = B * Hin * Wg * CoT;
    if (idx >= total) return;
    int cg = idx % CoT; int t = idx / CoT;
    int wg = t % Wg;    t /= Wg;
    int hi = t % Hin;   int b = t / Hin;
    int co = cg << 2;
    int wi = wg << 1;

    float4 bv = *reinterpret_cast<const float4*>(bias + co);
    float acc[2][4][4];
    #pragma unroll
    for (int oy = 0; oy < 2; ++oy)
        #pragma unroll
        for (int ox = 0; ox < 4; ++ox) {
            acc[oy][ox][0] = bv.x; acc[oy][ox][1] = bv.y;
            acc[oy][ox][2] = bv.z; acc[oy][ox][3] = bv.w;
        }

    const bool r1ok = (hi + 1) < Hin;
    const bool c1ok = (wi + 1) < Win;
    const bool c2ok = (wi + 2) < Win;

    for (int ci = 0; ci < Cin; ci += 4) {
        float P[2][3][4];
        #pragma unroll
        for (int r = 0; r < 2; ++r) {
            #pragma unroll
            for (int c = 0; c < 3; ++c) {
                bool ok = (r == 0 || r1ok) && (c == 0 || (c == 1 ? c1ok : c2ok));
                if (ok) {
                    const ushort_t* ip = in + ((long)(b * Hin + hi + r) * Win + wi + c) * Cin + ci;
                    ushort4 v = *reinterpret_cast<const ushort4*>(ip);
                    P[r][c][0] = bu2f(v.x); P[r][c][1] = bu2f(v.y);
                    P[r][c][2] = bu2f(v.z); P[r][c][3] = bu2f(v.w);
                } else {
                    P[r][c][0] = P[r][c][1] = P[r][c][2] = P[r][c][3] = 0.f;
                }
            }
        }
        #pragma unroll
        for (int dy = 0; dy < 3; ++dy) {
            #pragma unroll
            for (int dx = 0; dx < 3; ++dx) {
                const int oy  = (dy == 1) ? 0 : 1;     // output row parity this tap feeds
                const int ir  = (dy == 2) ? 1 : 0;     // input row it reads
                const int oxa = (dx == 1) ? 0 : 1;     // first of the two output cols
                const int ica = (dx == 2) ? 1 : 0;     // its input col
                const float* wp = wgt + ((long)(dy * 3 + dx) * Cin + ci) * Cout + co;
                float4 w0 = *reinterpret_cast<const float4*>(wp);
                float4 w1 = *reinterpret_cast<const float4*>(wp + Cout);
                float4 w2 = *reinterpret_cast<const float4*>(wp + 2 * Cout);
                float4 w3 = *reinterpret_cast<const float4*>(wp + 3 * Cout);
                #pragma unroll
                for (int q = 0; q < 2; ++q) {          // the tap's two (out,in) pairs
                    float* a = acc[oy][oxa + 2 * q];
                    const float* v = P[ir][ica + q];
                    a[0] = fmaf(v[0], w0.x, a[0]); a[1] = fmaf(v[0], w0.y, a[1]);
                    a[2] = fmaf(v[0], w0.z, a[2]); a[3] = fmaf(v[0], w0.w, a[3]);
                    a[0] = fmaf(v[1], w1.x, a[0]); a[1] = fmaf(v[1], w1.y, a[1]);
                    a[2] = fmaf(v[1], w1.z, a[2]); a[3] = fmaf(v[1], w1.w, a[3]);
                    a[0] = fmaf(v[2], w2.x, a[0]); a[1] = fmaf(v[2], w2.y, a[1]);
                    a[2] = fmaf(v[2], w2.z, a[2]); a[3] = fmaf(v[2], w2.w, a[3]);
                    a[0] = fmaf(v[3], w3.x, a[0]); a[1] = fmaf(v[3], w3.y, a[1]);
                    a[2] = fmaf(v[3], w3.z, a[2]); a[3] = fmaf(v[3], w3.w, a[3]);
                }
            }
        }
    }

    #pragma unroll
    for (int oy = 0; oy < 2; ++oy) {
        #pragma unroll
        for (int ox = 0; ox < 4; ++ox) {
            long o = ((long)(b * Ho + 2 * hi + oy) * Wo + 4 * wg + ox) * Cout + co;
            ushort4 sv = *reinterpret_cast<const ushort4*>(skip + o);
            ushort4 res;
            res.x = f2bu(lrelu(acc[oy][ox][0]) + bu2f(sv.x));
            res.y = f2bu(lrelu(acc[oy][ox][1]) + bu2f(sv.y));
            res.z = f2bu(lrelu(acc[oy][ox][2]) + bu2f(sv.z));
            res.w = f2bu(lrelu(acc[oy][ox][3]) + bu2f(sv.w));
            *reinterpret_cast<ushort4*>(out + o) = res;
        }
    }
}

// Fused final stage: dec0 (3x3 conv 16->16, bias+lrelu) + 1x1 conv 16->1
// + triangular mask + softplus on diagonal. 4-pixel blocked. bf16 in, f32 out.
__global__ __launch_bounds__(256) void dec0_out_mask_px4_kernel(
    const ushort_t* __restrict__ in,     // up0 [B,N,N,16] bf16
    const float* __restrict__ w_dec,     // [3,3,16,16]
    const float* __restrict__ b_dec,     // [16]
    const float* __restrict__ w_out,     // [16]
    const float* __restrict__ b_out,     // [1]
    float* __restrict__ out, int B, int N)
{
    const int W4 = N >> 2;
    int idx = blockIdx.x * 256 + threadIdx.x;
    int total = B * N * W4;
    if (idx >= total) return;
    int wg  = idx % W4; int t = idx / W4;
    int row = t % N;    int b = t / N;
    int wo0 = wg << 2;

    float acc[4][16];
    #pragma unroll
    for (int px = 0; px < 4; ++px)
        #pragma unroll
        for (int c = 0; c < 16; ++c) acc[px][c] = b_dec[c];

    for (int dy = 0; dy < 3; ++dy) {
        int hi = row + dy - 1;
        if ((unsigned)hi >= (unsigned)N) continue;
        const ushort_t* rowp = in + ((long)(b * N + hi) * N) * 16;
        for (int ci = 0; ci < 16; ci += 4) {
            float iv[6][4];
            #pragma unroll
            for (int c = 0; c < 6; ++c) {
                int wi = wo0 - 1 + c;
                if ((unsigned)wi < (unsigned)N) {
                    ushort4 v = *reinterpret_cast<const ushort4*>(rowp + (long)wi * 16 + ci);
                    iv[c][0] = bu2f(v.x); iv[c][1] = bu2f(v.y);
                    iv[c][2] = bu2f(v.z); iv[c][3] = bu2f(v.w);
                } else {
                    iv[c][0] = iv[c][1] = iv[c][2] = iv[c][3] = 0.f;
                }
            }
            #pragma unroll
            for (int dx = 0; dx < 3; ++dx) {
                #pragma unroll
                for (int k = 0; k < 4; ++k) {
                    const float* wr = w_dec + ((dy * 3 + dx) * 16 + ci + k) * 16;
                    float4 wa = *reinterpret_cast<const float4*>(wr);
                    float4 wb = *reinterpret_cast<const float4*>(wr + 4);
                    float4 wc = *reinterpret_cast<const float4*>(wr + 8);
                    float4 wd = *reinterpret_cast<const float4*>(wr + 12);
                    #pragma unroll
                    for (int px = 0; px < 4; ++px) {
                        float v = iv[px + dx][k];
                        acc[px][0]  = fmaf(v, wa.x, acc[px][0]);  acc[px][1]  = fmaf(v, wa.y, acc[px][1]);
                        acc[px][2]  = fmaf(v, wa.z, acc[px][2]);  acc[px][3]  = fmaf(v, wa.w, acc[px][3]);
                        acc[px][4]  = fmaf(v, wb.x, acc[px][4]);  acc[px][5]  = fmaf(v, wb.y, acc[px][5]);
                        acc[px][6]  = fmaf(v, wb.z, acc[px][6]);  acc[px][7]  = fmaf(v, wb.w, acc[px][7]);
                        acc[px][8]  = fmaf(v, wc.x, acc[px][8]);  acc[px][9]  = fmaf(v, wc.y, acc[px][9]);
                        acc[px][10] = fmaf(v, wc.z, acc[px][10]); acc[px][11] = fmaf(v, wc.w, acc[px][11]);
                        acc[px][12] = fmaf(v, wd.x, acc[px][12]); acc[px][13] = fmaf(v, wd.y, acc[px][13]);
                        acc[px][14] = fmaf(v, wd.z, acc[px][14]); acc[px][15] = fmaf(v, wd.w, acc[px][15]);
                    }
                }
            }
        }
    }

    float4 res;
    float* rp = &res.x;
    #pragma unroll
    for (int px = 0; px < 4; ++px) {
        float interim = b_out[0];
        #pragma unroll
        for (int c = 0; c < 16; ++c) interim = fmaf(lrelu(acc[px][c]), w_out[c], interim);
        int col = wo0 + px;
        float v;
        if (row < col) {
            v = 0.f;
        } else if (row == col) {
            v = fmaxf(interim, 0.f) + log1pf(expf(-fabsf(interim)));  // stable softplus
        } else {
            v = interim;
        }
        rp[px] = v;
    }
    *reinterpret_cast<float4*>(out + ((long)(b * N + row) * N + wo0)) = res;
}

extern "C" void kernel_launch(void* const* d_in, const int* in_sizes, int n_in,
                              void* d_out, int out_size, void* d_ws, size_t ws_size,
                              hipStream_t stream)
{
    const float* x      = (const float*)d_in[0];
    const float* w_enc1 = (const float*)d_in[1];  const float* b_enc1 = (const float*)d_in[2];
    const float* w_down1= (const float*)d_in[3];  const float* b_down1= (const float*)d_in[4];
    const float* w_enc2 = (const float*)d_in[5];  const float* b_enc2 = (const float*)d_in[6];
    const float* w_down2= (const float*)d_in[7];  const float* b_down2= (const float*)d_in[8];
    const float* w_enc3 = (const float*)d_in[9];  const float* b_enc3 = (const float*)d_in[10];
    const float* w_bn   = (const float*)d_in[11]; const float* b_bn   = (const float*)d_in[12];
    const float* w_up2  = (const float*)d_in[13]; const float* b_up2  = (const float*)d_in[14];
    const float* w_dec2 = (const float*)d_in[15]; const float* b_dec2 = (const float*)d_in[16];
    const float* w_up1  = (const float*)d_in[17]; const float* b_up1  = (const float*)d_in[18];
    const float* w_dec1 = (const float*)d_in[19]; const float* b_dec1 = (const float*)d_in[20];
    const float* w_up0  = (const float*)d_in[21]; const float* b_up0  = (const float*)d_in[22];
    const float* w_dec0 = (const float*)d_in[23]; const float* b_dec0 = (const float*)d_in[24];
    const float* w_out  = (const float*)d_in[25]; const float* b_out  = (const float*)d_in[26];

    // Workspace layout in bf16 elements. Total 88,080,384 elems = 168 MB.
    ushort_t* ws   = (ushort_t*)d_ws;
    ushort_t* E1   = ws;                 // [8,512,512,16] enc1, later up0 (in-place)
    ushort_t* T256 = E1   + 33554432;    // [8,256,256,32] down1, later up1
    ushort_t* E2   = T256 + 16777216;    // [8,256,256,32] enc2, later dec1
    ushort_t* T128 = E2   + 16777216;    // [8,128,128,64] down2, later up2
    ushort_t* E3   = T128 + 8388608;     // [8,128,128,64] enc3, later dec2
    ushort_t* T64  = E3   + 8388608;     // [8, 64, 64,128] bneck

    const size_t needed = 88080384ull * sizeof(ushort_t);
    if (ws_size < needed) {
        hipMemsetAsync(d_out, 0, (size_t)out_size * sizeof(float), stream);
        return;
    }

    const int B = 8;
    auto conv1 = [&](const auto* in, const float* w, const float* bias, ushort_t* out,
                     int Hin, int Cin, int Cout) {
        int total = B * Hin * (Hin >> 2) * (Cout >> 2);
        using Tin = std::remove_const_t<std::remove_pointer_t<decltype(in)>>;
        hipLaunchKernelGGL((conv3x3_px4_kernel<Tin, 1>), dim3((total + 255) / 256), dim3(256), 0, stream,
                           in, w, bias, out, B, Hin, Hin, Cin, Cout, Hin, Hin);
    };
    auto conv2 = [&](const ushort_t* in, const float* w, const float* bias, ushort_t* out,
                     int Hin, int Cin, int Cout) {
        int Ho = Hin >> 1;
        int total = B * Ho * (Ho >> 2) * (Cout >> 2);
        hipLaunchKernelGGL((conv3x3_px4_kernel<ushort_t, 2>), dim3((total + 255) / 256), dim3(256), 0, stream,
                           in, w, bias, out, B, Hin, Hin, Cin, Cout, Ho, Ho);
    };
    auto tconv = [&](const ushort_t* in, const float* w, const float* bias, const ushort_t* skip,
                     ushort_t* out, int Hin, int Cin, int Cout) {
        int total = B * Hin * (Hin >> 1) * (Cout >> 2);
        hipLaunchKernelGGL(tconv3x3_q8_kernel, dim3((total + 255) / 256), dim3(256), 0, stream,
                           in, w, bias, skip, out, B, Hin, Hin, Cin, Cout);
    };

    conv1(x,    w_enc1,  b_enc1,  E1,   512,   1,  16);       // enc1
    conv2(E1,   w_down1, b_down1, T256, 512,  16,  32);       // down1
    conv1(T256, w_enc2,  b_enc2,  E2,   256,  32,  32);       // enc2
    conv2(E2,   w_down2, b_down2, T128, 256,  32,  64);       // down2
    conv1(T128, w_enc3,  b_enc3,  E3,   128,  64,  64);       // enc3
    conv2(E3,   w_bn,    b_bn,    T64,  128,  64, 128);       // bneck
    tconv(T64,  w_up2,   b_up2,   E3,   T128,  64, 128,  64); // up2 = lrelu(tconv)+enc3
    conv1(T128, w_dec2,  b_dec2,  E3,   128,  64,  64);       // dec2 (E3 dead -> reuse)
    tconv(E3,   w_up1,   b_up1,   E2,   T256, 128,  64,  32); // up1 = +enc2
    conv1(T256, w_dec1,  b_dec1,  E2,   256,  32,  32);       // dec1 (E2 dead -> reuse)
    tconv(E2,   w_up0,   b_up0,   E1,   E1,   256,  32,  16); // up0 = +enc1 (in-place)

    int total = B * 512 * 128;
    hipLaunchKernelGGL(dec0_out_mask_px4_kernel, dim3((total + 255) / 256), dim3(256), 0, stream,
                       E1, w_dec0, b_dec0, w_out, b_out, (float*)d_out, B, 512);
}

// Round 6
// 2610.097 us; speedup vs baseline: 2.4874x; 1.1192x over previous
//
#include <hip/hip_runtime.h>
#include <math.h>
#include <type_traits>

typedef unsigned short ushort_t;

__device__ __forceinline__ float lrelu(float x) { return x >= 0.f ? x : 0.01f * x; }

// bf16 (raw ushort) <-> f32, RNE rounding.
__device__ __forceinline__ float bu2f(ushort_t u) {
    unsigned int x = ((unsigned int)u) << 16;
    float f; __builtin_memcpy(&f, &x, 4); return f;
}
__device__ __forceinline__ ushort_t f2bu(float f) {
    unsigned int x; __builtin_memcpy(&x, &f, 4);
    unsigned int r = (x + 0x7FFFu + ((x >> 16) & 1u)) >> 16;
    return (ushort_t)r;
}

// 3x3 conv, pad=1, NHWC, fused bias+LeakyReLU, bf16 out.
// Compile-time CIN/COUT/STRIDE: constant-folded addressing + ci-loop unroll x2
// (load-all-then-FMA) to maximize loads in flight. 4 px x 4 Cout per thread.
template <typename Tin, int CIN, int COUT, int STRIDE>
__global__ __launch_bounds__(256) void conv3x3_t(
    const Tin* __restrict__ in, const float* __restrict__ wgt,
    const float* __restrict__ bias, ushort_t* __restrict__ out,
    int B, int Hin)
{
    const int Win = Hin;
    const int Ho = Hin / STRIDE, Wo = Win / STRIDE;
    constexpr int NC = 3 * STRIDE + 3;   // input columns touched by 4 outputs
    constexpr int CoT = COUT >> 2;
    const int Wo4 = Wo >> 2;
    int idx = blockIdx.x * 256 + threadIdx.x;
    int total = B * Ho * Wo4 * CoT;
    if (idx >= total) return;
    int cg = idx % CoT; int t = idx / CoT;
    int wg = t % Wo4;   t /= Wo4;
    int ho = t % Ho;    int b = t / Ho;
    int co = cg << 2;
    int wo0 = wg << 2;

    float4 bv = *reinterpret_cast<const float4*>(bias + co);
    float acc[4][4];
    #pragma unroll
    for (int px = 0; px < 4; ++px) {
        acc[px][0] = bv.x; acc[px][1] = bv.y; acc[px][2] = bv.z; acc[px][3] = bv.w;
    }

    const int hb  = ho * STRIDE - 1;
    const int wb0 = wo0 * STRIDE - 1;

    if constexpr (CIN == 1) {
        for (int dy = 0; dy < 3; ++dy) {
            int hi = hb + dy;
            if ((unsigned)hi >= (unsigned)Hin) continue;
            const Tin* rowp = in + (long)(b * Hin + hi) * Win;
            float iv[NC];
            #pragma unroll
            for (int c = 0; c < NC; ++c) {
                int wi = wb0 + c;
                float v = 0.f;
                if ((unsigned)wi < (unsigned)Win) {
                    if constexpr (std::is_same<Tin, float>::value) v = rowp[wi];
                    else v = bu2f(rowp[wi]);
                }
                iv[c] = v;
            }
            #pragma unroll
            for (int dx = 0; dx < 3; ++dx) {
                const float* wp = wgt + (dy * 3 + dx) * COUT + co;
                float4 w = *reinterpret_cast<const float4*>(wp);
                #pragma unroll
                for (int px = 0; px < 4; ++px) {
                    float v = iv[px * STRIDE + dx];
                    acc[px][0] = fmaf(v, w.x, acc[px][0]); acc[px][1] = fmaf(v, w.y, acc[px][1]);
                    acc[px][2] = fmaf(v, w.z, acc[px][2]); acc[px][3] = fmaf(v, w.w, acc[px][3]);
                }
            }
        }
    } else {
        constexpr int CG  = CIN / 4;           // ci groups of 4
        constexpr int UNR = (CG >= 2) ? 2 : 1; // groups unrolled per outer iter
        for (int dy = 0; dy < 3; ++dy) {
            int hi = hb + dy;
            if ((unsigned)hi >= (unsigned)Hin) continue;
            const Tin* rowp = in + ((long)(b * Hin + hi) * Win) * CIN;
            #pragma unroll 1
            for (int cc = 0; cc < CG; cc += UNR) {
                float iv[UNR][NC][4];
                #pragma unroll
                for (int u = 0; u < UNR; ++u) {
                    int ci = (cc + u) << 2;
                    #pragma unroll
                    for (int c = 0; c < NC; ++c) {
                        int wi = wb0 + c;
                        if ((unsigned)wi < (unsigned)Win) {
                            if constexpr (std::is_same<Tin, float>::value) {
                                float4 v = *reinterpret_cast<const float4*>(rowp + (long)wi * CIN + ci);
                                iv[u][c][0] = v.x; iv[u][c][1] = v.y; iv[u][c][2] = v.z; iv[u][c][3] = v.w;
                            } else {
                                ushort4 v = *reinterpret_cast<const ushort4*>(rowp + (long)wi * CIN + ci);
                                iv[u][c][0] = bu2f(v.x); iv[u][c][1] = bu2f(v.y);
                                iv[u][c][2] = bu2f(v.z); iv[u][c][3] = bu2f(v.w);
                            }
                        } else {
                            iv[u][c][0] = iv[u][c][1] = iv[u][c][2] = iv[u][c][3] = 0.f;
                        }
                    }
                }
                #pragma unroll
                for (int u = 0; u < UNR; ++u) {
                    int ci = (cc + u) << 2;
                    #pragma unroll
                    for (int dx = 0; dx < 3; ++dx) {
                        const float* wp = wgt + ((dy * 3 + dx) * CIN + ci) * COUT + co;
                        float4 w0 = *reinterpret_cast<const float4*>(wp);
                        float4 w1 = *reinterpret_cast<const float4*>(wp + COUT);
                        float4 w2 = *reinterpret_cast<const float4*>(wp + 2 * COUT);
                        float4 w3 = *reinterpret_cast<const float4*>(wp + 3 * COUT);
                        #pragma unroll
                        for (int px = 0; px < 4; ++px) {
                            const float* v = iv[u][px * STRIDE + dx];
                            acc[px][0] = fmaf(v[0], w0.x, acc[px][0]); acc[px][1] = fmaf(v[0], w0.y, acc[px][1]);
                            acc[px][2] = fmaf(v[0], w0.z, acc[px][2]); acc[px][3] = fmaf(v[0], w0.w, acc[px][3]);
                            acc[px][0] = fmaf(v[1], w1.x, acc[px][0]); acc[px][1] = fmaf(v[1], w1.y, acc[px][1]);
                            acc[px][2] = fmaf(v[1], w1.z, acc[px][2]); acc[px][3] = fmaf(v[1], w1.w, acc[px][3]);
                            acc[px][0] = fmaf(v[2], w2.x, acc[px][0]); acc[px][1] = fmaf(v[2], w2.y, acc[px][1]);
                            acc[px][2] = fmaf(v[2], w2.z, acc[px][2]); acc[px][3] = fmaf(v[2], w2.w, acc[px][3]);
                            acc[px][0] = fmaf(v[3], w3.x, acc[px][0]); acc[px][1] = fmaf(v[3], w3.y, acc[px][1]);
                            acc[px][2] = fmaf(v[3], w3.z, acc[px][2]); acc[px][3] = fmaf(v[3], w3.w, acc[px][3]);
                        }
                    }
                }
            }
        }
    }

    #pragma unroll
    for (int px = 0; px < 4; ++px) {
        ushort4 res;
        res.x = f2bu(lrelu(acc[px][0])); res.y = f2bu(lrelu(acc[px][1]));
        res.z = f2bu(lrelu(acc[px][2])); res.w = f2bu(lrelu(acc[px][3]));
        *reinterpret_cast<ushort4*>(out + ((long)(b * Ho + ho) * Wo + wo0 + px) * COUT + co) = res;
    }
}

// Transposed conv k=3, lhs_dilation=2, pad(1,2): output doubles H,W.
// 2x4 output block x 4 Cout per thread from a 2x3 input patch. Tap (dy,dx)
// feeds exactly 2 of the 8 outputs. Compile-time CIN/COUT + unroll x2.
// Fused bias+lrelu+skip (skip may alias out; same-thread same-index rw).
template <int CIN, int COUT>
__global__ __launch_bounds__(256) void tconv3x3_t(
    const ushort_t* __restrict__ in, const float* __restrict__ wgt,
    const float* __restrict__ bias, const ushort_t* __restrict__ skip,
    ushort_t* __restrict__ out,
    int B, int Hin)
{
    const int Win = Hin;
    const int Ho = Hin * 2, Wo = Win * 2;
    constexpr int CoT = COUT >> 2;
    const int Wg = Win >> 1;            // 4 output cols per thread = 2 input cols
    int idx = blockIdx.x * 256 + threadIdx.x;
    int total = B * Hin * Wg * CoT;
    if (idx >= total) return;
    int cg = idx % CoT; int t = idx / CoT;
    int wg = t % Wg;    t /= Wg;
    int hi = t % Hin;   int b = t / Hin;
    int co = cg << 2;
    int wi = wg << 1;

    float4 bv = *reinterpret_cast<const float4*>(bias + co);
    float acc[2][4][4];
    #pragma unroll
    for (int oy = 0; oy < 2; ++oy)
        #pragma unroll
        for (int ox = 0; ox < 4; ++ox) {
            acc[oy][ox][0] = bv.x; acc[oy][ox][1] = bv.y;
            acc[oy][ox][2] = bv.z; acc[oy][ox][3] = bv.w;
        }

    const bool r1ok = (hi + 1) < Hin;
    const bool c1ok = (wi + 1) < Win;
    const bool c2ok = (wi + 2) < Win;

    constexpr int CG  = CIN / 4;
    constexpr int UNR = (CG >= 2) ? 2 : 1;
    #pragma unroll 1
    for (int cc = 0; cc < CG; cc += UNR) {
        float P[UNR][2][3][4];
        #pragma unroll
        for (int u = 0; u < UNR; ++u) {
            int ci = (cc + u) << 2;
            #pragma unroll
            for (int r = 0; r < 2; ++r) {
                #pragma unroll
                for (int c = 0; c < 3; ++c) {
                    bool ok = (r == 0 || r1ok) && (c == 0 || (c == 1 ? c1ok : c2ok));
                    if (ok) {
                        const ushort_t* ip = in + ((long)(b * Hin + hi + r) * Win + wi + c) * CIN + ci;
                        ushort4 v = *reinterpret_cast<const ushort4*>(ip);
                        P[u][r][c][0] = bu2f(v.x); P[u][r][c][1] = bu2f(v.y);
                        P[u][r][c][2] = bu2f(v.z); P[u][r][c][3] = bu2f(v.w);
                    } else {
                        P[u][r][c][0] = P[u][r][c][1] = P[u][r][c][2] = P[u][r][c][3] = 0.f;
                    }
                }
            }
        }
        #pragma unroll
        for (int u = 0; u < UNR; ++u) {
            int ci = (cc + u) << 2;
            #pragma unroll
            for (int dy = 0; dy < 3; ++dy) {
                #pragma unroll
                for (int dx = 0; dx < 3; ++dx) {
                    const int oy  = (dy == 1) ? 0 : 1;     // output row parity this tap feeds
                    const int ir  = (dy == 2) ? 1 : 0;     // input row it reads
                    const int oxa = (dx == 1) ? 0 : 1;     // first of the two output cols
                    const int ica = (dx == 2) ? 1 : 0;     // its input col
                    const float* wp = wgt + ((dy * 3 + dx) * CIN + ci) * COUT + co;
                    float4 w0 = *reinterpret_cast<const float4*>(wp);
                    float4 w1 = *reinterpret_cast<const float4*>(wp + COUT);
                    float4 w2 = *reinterpret_cast<const float4*>(wp + 2 * COUT);
                    float4 w3 = *reinterpret_cast<const float4*>(wp + 3 * COUT);
                    #pragma unroll
                    for (int q = 0; q < 2; ++q) {          // the tap's two (out,in) pairs
                        float* a = acc[oy][oxa + 2 * q];
                        const float* v = P[u][ir][ica + q];
                        a[0] = fmaf(v[0], w0.x, a[0]); a[1] = fmaf(v[0], w0.y, a[1]);
                        a[2] = fmaf(v[0], w0.z, a[2]); a[3] = fmaf(v[0], w0.w, a[3]);
                        a[0] = fmaf(v[1], w1.x, a[0]); a[1] = fmaf(v[1], w1.y, a[1]);
                        a[2] = fmaf(v[1], w1.z, a[2]); a[3] = fmaf(v[1], w1.w, a[3]);
                        a[0] = fmaf(v[2], w2.x, a[0]); a[1] = fmaf(v[2], w2.y, a[1]);
                        a[2] = fmaf(v[2], w2.z, a[2]); a[3] = fmaf(v[2], w2.w, a[3]);
                        a[0] = fmaf(v[3], w3.x, a[0]); a[1] = fmaf(v[3], w3.y, a[1]);
                        a[2] = fmaf(v[3], w3.z, a[2]); a[3] = fmaf(v[3], w3.w, a[3]);
                    }
                }
            }
        }
    }

    #pragma unroll
    for (int oy = 0; oy < 2; ++oy) {
        #pragma unroll
        for (int ox = 0; ox < 4; ++ox) {
            long o = ((long)(b * Ho + 2 * hi + oy) * Wo + 4 * wg + ox) * COUT + co;
            ushort4 sv = *reinterpret_cast<const ushort4*>(skip + o);
            ushort4 res;
            res.x = f2bu(lrelu(acc[oy][ox][0]) + bu2f(sv.x));
            res.y = f2bu(lrelu(acc[oy][ox][1]) + bu2f(sv.y));
            res.z = f2bu(lrelu(acc[oy][ox][2]) + bu2f(sv.z));
            res.w = f2bu(lrelu(acc[oy][ox][3]) + bu2f(sv.w));
            *reinterpret_cast<ushort4*>(out + o) = res;
        }
    }
}

// Fused final stage: dec0 (3x3 conv 16->16, bias+lrelu) + 1x1 conv 16->1
// + triangular mask + softplus on diagonal. 4-pixel blocked. bf16 in, f32 out.
__global__ __launch_bounds__(256) void dec0_out_mask_px4_kernel(
    const ushort_t* __restrict__ in,     // up0 [B,N,N,16] bf16
    const float* __restrict__ w_dec,     // [3,3,16,16]
    const float* __restrict__ b_dec,     // [16]
    const float* __restrict__ w_out,     // [16]
    const float* __restrict__ b_out,     // [1]
    float* __restrict__ out, int B, int N)
{
    const int W4 = N >> 2;
    int idx = blockIdx.x * 256 + threadIdx.x;
    int total = B * N * W4;
    if (idx >= total) return;
    int wg  = idx % W4; int t = idx / W4;
    int row = t % N;    int b = t / N;
    int wo0 = wg << 2;

    float acc[4][16];
    #pragma unroll
    for (int px = 0; px < 4; ++px)
        #pragma unroll
        for (int c = 0; c < 16; ++c) acc[px][c] = b_dec[c];

    for (int dy = 0; dy < 3; ++dy) {
        int hi = row + dy - 1;
        if ((unsigned)hi >= (unsigned)N) continue;
        const ushort_t* rowp = in + ((long)(b * N + hi) * N) * 16;
        #pragma unroll 1
        for (int ci = 0; ci < 16; ci += 4) {
            float iv[6][4];
            #pragma unroll
            for (int c = 0; c < 6; ++c) {
                int wi = wo0 - 1 + c;
                if ((unsigned)wi < (unsigned)N) {
                    ushort4 v = *reinterpret_cast<const ushort4*>(rowp + (long)wi * 16 + ci);
                    iv[c][0] = bu2f(v.x); iv[c][1] = bu2f(v.y);
                    iv[c][2] = bu2f(v.z); iv[c][3] = bu2f(v.w);
                } else {
                    iv[c][0] = iv[c][1] = iv[c][2] = iv[c][3] = 0.f;
                }
            }
            #pragma unroll
            for (int dx = 0; dx < 3; ++dx) {
                #pragma unroll
                for (int k = 0; k < 4; ++k) {
                    const float* wr = w_dec + ((dy * 3 + dx) * 16 + ci + k) * 16;
                    float4 wa = *reinterpret_cast<const float4*>(wr);
                    float4 wb = *reinterpret_cast<const float4*>(wr + 4);
                    float4 wc = *reinterpret_cast<const float4*>(wr + 8);
                    float4 wd = *reinterpret_cast<const float4*>(wr + 12);
                    #pragma unroll
                    for (int px = 0; px < 4; ++px) {
                        float v = iv[px + dx][k];
                        acc[px][0]  = fmaf(v, wa.x, acc[px][0]);  acc[px][1]  = fmaf(v, wa.y, acc[px][1]);
                        acc[px][2]  = fmaf(v, wa.z, acc[px][2]);  acc[px][3]  = fmaf(v, wa.w, acc[px][3]);
                        acc[px][4]  = fmaf(v, wb.x, acc[px][4]);  acc[px][5]  = fmaf(v, wb.y, acc[px][5]);
                        acc[px][6]  = fmaf(v, wb.z, acc[px][6]);  acc[px][7]  = fmaf(v, wb.w, acc[px][7]);
                        acc[px][8]  = fmaf(v, wc.x, acc[px][8]);  acc[px][9]  = fmaf(v, wc.y, acc[px][9]);
                        acc[px][10] = fmaf(v, wc.z, acc[px][10]); acc[px][11] = fmaf(v, wc.w, acc[px][11]);
                        acc[px][12] = fmaf(v, wd.x, acc[px][12]); acc[px][13] = fmaf(v, wd.y, acc[px][13]);
                        acc[px][14] = fmaf(v, wd.z, acc[px][14]); acc[px][15] = fmaf(v, wd.w, acc[px][15]);
                    }
                }
            }
        }
    }

    float4 res;
    float* rp = &res.x;
    #pragma unroll
    for (int px = 0; px < 4; ++px) {
        float interim = b_out[0];
        #pragma unroll
        for (int c = 0; c < 16; ++c) interim = fmaf(lrelu(acc[px][c]), w_out[c], interim);
        int col = wo0 + px;
        float v;
        if (row < col) {
            v = 0.f;
        } else if (row == col) {
            v = fmaxf(interim, 0.f) + log1pf(expf(-fabsf(interim)));  // stable softplus
        } else {
            v = interim;
        }
        rp[px] = v;
    }
    *reinterpret_cast<float4*>(out + ((long)(b * N + row) * N + wo0)) = res;
}

template <typename Tin, int CIN, int COUT, int STRIDE>
static void launch_conv(const Tin* in, const float* w, const float* bias, ushort_t* out,
                        int Hin, hipStream_t stream)
{
    int Ho = Hin / STRIDE;
    int total = 8 * Ho * (Ho >> 2) * (COUT >> 2);
    hipLaunchKernelGGL((conv3x3_t<Tin, CIN, COUT, STRIDE>), dim3((total + 255) / 256), dim3(256),
                       0, stream, in, w, bias, out, 8, Hin);
}

template <int CIN, int COUT>
static void launch_tconv(const ushort_t* in, const float* w, const float* bias,
                         const ushort_t* skip, ushort_t* out, int Hin, hipStream_t stream)
{
    int total = 8 * Hin * (Hin >> 1) * (COUT >> 2);
    hipLaunchKernelGGL((tconv3x3_t<CIN, COUT>), dim3((total + 255) / 256), dim3(256),
                       0, stream, in, w, bias, skip, out, 8, Hin);
}

extern "C" void kernel_launch(void* const* d_in, const int* in_sizes, int n_in,
                              void* d_out, int out_size, void* d_ws, size_t ws_size,
                              hipStream_t stream)
{
    const float* x      = (const float*)d_in[0];
    const float* w_enc1 = (const float*)d_in[1];  const float* b_enc1 = (const float*)d_in[2];
    const float* w_down1= (const float*)d_in[3];  const float* b_down1= (const float*)d_in[4];
    const float* w_enc2 = (const float*)d_in[5];  const float* b_enc2 = (const float*)d_in[6];
    const float* w_down2= (const float*)d_in[7];  const float* b_down2= (const float*)d_in[8];
    const float* w_enc3 = (const float*)d_in[9];  const float* b_enc3 = (const float*)d_in[10];
    const float* w_bn   = (const float*)d_in[11]; const float* b_bn   = (const float*)d_in[12];
    const float* w_up2  = (const float*)d_in[13]; const float* b_up2  = (const float*)d_in[14];
    const float* w_dec2 = (const float*)d_in[15]; const float* b_dec2 = (const float*)d_in[16];
    const float* w_up1  = (const float*)d_in[17]; const float* b_up1  = (const float*)d_in[18];
    const float* w_dec1 = (const float*)d_in[19]; const float* b_dec1 = (const float*)d_in[20];
    const float* w_up0  = (const float*)d_in[21]; const float* b_up0  = (const float*)d_in[22];
    const float* w_dec0 = (const float*)d_in[23]; const float* b_dec0 = (const float*)d_in[24];
    const float* w_out  = (const float*)d_in[25]; const float* b_out  = (const float*)d_in[26];

    // Workspace layout in bf16 elements. Total 88,080,384 elems = 168 MB.
    ushort_t* ws   = (ushort_t*)d_ws;
    ushort_t* E1   = ws;                 // [8,512,512,16] enc1, later up0 (in-place)
    ushort_t* T256 = E1   + 33554432;    // [8,256,256,32] down1, later up1
    ushort_t* E2   = T256 + 16777216;    // [8,256,256,32] enc2, later dec1
    ushort_t* T128 = E2   + 16777216;    // [8,128,128,64] down2, later up2
    ushort_t* E3   = T128 + 8388608;     // [8,128,128,64] enc3, later dec2
    ushort_t* T64  = E3   + 8388608;     // [8, 64, 64,128] bneck

    const size_t needed = 88080384ull * sizeof(ushort_t);
    if (ws_size < needed) {
        hipMemsetAsync(d_out, 0, (size_t)out_size * sizeof(float), stream);
        return;
    }

    launch_conv<float,    1,  16, 1>(x,    w_enc1,  b_enc1,  E1,   512, stream);  // enc1
    launch_conv<ushort_t, 16, 32, 2>(E1,   w_down1, b_down1, T256, 512, stream);  // down1
    launch_conv<ushort_t, 32, 32, 1>(T256, w_enc2,  b_enc2,  E2,   256, stream);  // enc2
    launch_conv<ushort_t, 32, 64, 2>(E2,   w_down2, b_down2, T128, 256, stream);  // down2
    launch_conv<ushort_t, 64, 64, 1>(T128, w_enc3,  b_enc3,  E3,   128, stream);  // enc3
    launch_conv<ushort_t, 64,128, 2>(E3,   w_bn,    b_bn,    T64,  128, stream);  // bneck
    launch_tconv<128, 64>(T64,  w_up2, b_up2, E3,   T128, 64,  stream);           // up2 = +enc3
    launch_conv<ushort_t, 64, 64, 1>(T128, w_dec2,  b_dec2,  E3,   128, stream);  // dec2 (E3 reuse)
    launch_tconv<64, 32>(E3,   w_up1, b_up1, E2,   T256, 128, stream);            // up1 = +enc2
    launch_conv<ushort_t, 32, 32, 1>(T256, w_dec1,  b_dec1,  E2,   256, stream);  // dec1 (E2 reuse)
    launch_tconv<32, 16>(E2,   w_up0, b_up0, E1,   E1,   256, stream);            // up0 = +enc1 (in-place)

    int total = 8 * 512 * 128;
    hipLaunchKernelGGL(dec0_out_mask_px4_kernel, dim3((total + 255) / 256), dim3(256), 0, stream,
                       E1, w_dec0, b_dec0, w_out, b_out, (float*)d_out, 8, 512);
}

// Round 11
// 1304.911 us; speedup vs baseline: 4.9754x; 2.0002x over previous
//
#include <hip/hip_runtime.h>
#include <math.h>
#include <type_traits>

typedef unsigned short ushort_t;
typedef __attribute__((ext_vector_type(8))) short bf16x8;
typedef __attribute__((ext_vector_type(4))) float f32x4;

__device__ __forceinline__ float lrelu(float x) { return x >= 0.f ? x : 0.01f * x; }

// bf16 (raw ushort) <-> f32, RNE rounding.
__device__ __forceinline__ float bu2f(ushort_t u) {
    unsigned int x = ((unsigned int)u) << 16;
    float f; __builtin_memcpy(&f, &x, 4); return f;
}
__device__ __forceinline__ ushort_t f2bu(float f) {
    unsigned int x; __builtin_memcpy(&x, &f, 4);
    unsigned int r = (x + 0x7FFFu + ((x >> 16) & 1u)) >> 16;
    return (ushort_t)r;
}

// ---------------------------------------------------------------------------
// Weight repack: f32 [3,3,CIN,COUT] -> bf16 B-fragment order
// dst[(((tap*KS+kg)*NG+ng)*64+lane)*8+j] = w[tap][kg*32+8*(lane>>4)+j][ng*16+(lane&15)]
// (zero-padded where ci >= CIN). Runs every call; lands in d_out scratch.
// ---------------------------------------------------------------------------
struct RepackDesc { const float* src; int dst_off; int cin; int cout; int count; };
struct RepackArgs { RepackDesc d[7]; };

__global__ __launch_bounds__(256) void repack_weights(RepackArgs args, ushort_t* dst, int total)
{
    int idx = blockIdx.x * 256 + threadIdx.x;
    if (idx >= total) return;
    int l = 0, base = 0;
    #pragma unroll
    for (int i = 0; i < 7; ++i) {
        bool here = (idx >= base) && (idx < base + args.d[i].count);
        if (here) l = i;
        base += args.d[i].count;
    }
    // recompute base for chosen l
    base = 0;
    for (int i = 0; i < l; ++i) base += args.d[i].count;
    RepackDesc dsc = args.d[l];
    int local = idx - base;
    int j    = local & 7;
    int lane = (local >> 3) & 63;
    int rest = local >> 9;
    int NG = dsc.cout >> 4;
    int KS = (dsc.cin + 31) >> 5;
    int ng  = rest % NG; rest /= NG;
    int kg  = rest % KS;
    int tap = rest / KS;
    int ci = kg * 32 + ((lane >> 4) << 3) + j;
    int co = (ng << 4) + (lane & 15);
    float v = (ci < dsc.cin) ? dsc.src[((long)tap * dsc.cin + ci) * dsc.cout + co] : 0.f;
    dst[dsc.dst_off + local] = f2bu(v);
}

// ---------------------------------------------------------------------------
// Implicit-GEMM MFMA 3x3 conv, pad=1, stride 1/2, NHWC bf16 -> bf16.
// Wave tile: 32 output pixels (along w) x 16 couts. K-loop: 9 taps x CIN/32.
// A: row=lane&15 (pixel), k=8*(lane>>4)+j (cin)  [16B/lane]
// B: col=lane&15 (cout),  k=8*(lane>>4)+j        [16B/lane, repacked]
// D: col=lane&15 (cout),  row=4*(lane>>4)+reg (pixel)
// ---------------------------------------------------------------------------
template <int CIN, int COUT, int STRIDE>
__global__ __launch_bounds__(256) void conv3x3_mfma(
    const ushort_t* __restrict__ in, const ushort_t* __restrict__ wB,
    const float* __restrict__ bias, ushort_t* __restrict__ out, int Hin)
{
    const int Win = Hin, Ho = Hin / STRIDE, Wo = Win / STRIDE;
    constexpr int KS = (CIN + 31) >> 5;
    constexpr int NG = COUT >> 4;
    const int lane = threadIdx.x & 63;
    const int kq = lane >> 4, mn = lane & 15;
    const int wg = Wo >> 5;
    long tile = (long)blockIdx.x * 4 + (threadIdx.x >> 6);
    long ntiles = (long)8 * Ho * wg * NG;
    if (tile >= ntiles) return;
    int ng = (int)(tile % NG); long t2 = tile / NG;
    int wgi = (int)(t2 % wg); t2 /= wg;
    int ho = (int)(t2 % Ho); int b = (int)(t2 / Ho);
    int wo0 = wgi << 5;
    int co0 = ng << 4;

    f32x4 acc0 = {0.f, 0.f, 0.f, 0.f}, acc1 = {0.f, 0.f, 0.f, 0.f};
    const bf16x8 zero = {};

    const int px0 = wo0 + mn;        // A row -> output pixel (first 16)
    const int ciofs = kq << 3;       // cin offset within 32-slice

    #pragma unroll
    for (int dy = 0; dy < 3; ++dy) {
        int ih = ho * STRIDE + dy - 1;
        if ((unsigned)ih >= (unsigned)Hin) continue;
        const ushort_t* rowb = in + (long)(b * Hin + ih) * Win * CIN;
        #pragma unroll
        for (int dx = 0; dx < 3; ++dx) {
            int iw0 = px0 * STRIDE + dx - 1;
            int iw1 = iw0 + 16 * STRIDE;
            bool ok0 = (unsigned)iw0 < (unsigned)Win;
            bool ok1 = (unsigned)iw1 < (unsigned)Win;
            int c0 = ok0 ? iw0 : 0;
            int c1 = ok1 ? iw1 : 0;
            #pragma unroll
            for (int kg = 0; kg < KS; ++kg) {
                bf16x8 a0 = *reinterpret_cast<const bf16x8*>(rowb + (long)c0 * CIN + kg * 32 + ciofs);
                bf16x8 a1 = *reinterpret_cast<const bf16x8*>(rowb + (long)c1 * CIN + kg * 32 + ciofs);
                if (!ok0) a0 = zero;
                if (!ok1) a1 = zero;
                const ushort_t* wp = wB + (long)((((dy * 3 + dx) * KS + kg) * NG + ng) * 64 + lane) * 8;
                bf16x8 bw = *reinterpret_cast<const bf16x8*>(wp);
                acc0 = __builtin_amdgcn_mfma_f32_16x16x32_bf16(a0, bw, acc0, 0, 0, 0);
                acc1 = __builtin_amdgcn_mfma_f32_16x16x32_bf16(a1, bw, acc1, 0, 0, 0);
            }
        }
    }

    float bv = bias[co0 + mn];
    #pragma unroll
    for (int r = 0; r < 4; ++r) {
        int prow = (kq << 2) + r;     // pixel within 16-group
        long o0 = ((long)(b * Ho + ho) * Wo + wo0 + prow) * COUT + co0 + mn;
        out[o0]             = f2bu(lrelu(acc0[r] + bv));
        out[o0 + 16 * COUT] = f2bu(lrelu(acc1[r] + bv));
    }
}

// ---------------------------------------------------------------------------
// VALU kernels kept from round 6: enc1 (Cin=1), tconv, fused dec0+1x1+mask.
// ---------------------------------------------------------------------------
template <typename Tin, int CIN, int COUT, int STRIDE>
__global__ __launch_bounds__(256) void conv3x3_t(
    const Tin* __restrict__ in, const float* __restrict__ wgt,
    const float* __restrict__ bias, ushort_t* __restrict__ out,
    int B, int Hin)
{
    const int Win = Hin;
    const int Ho = Hin / STRIDE, Wo = Win / STRIDE;
    constexpr int NC = 3 * STRIDE + 3;
    constexpr int CoT = COUT >> 2;
    const int Wo4 = Wo >> 2;
    int idx = blockIdx.x * 256 + threadIdx.x;
    int total = B * Ho * Wo4 * CoT;
    if (idx >= total) return;
    int cg = idx % CoT; int t = idx / CoT;
    int wg = t % Wo4;   t /= Wo4;
    int ho = t % Ho;    int b = t / Ho;
    int co = cg << 2;
    int wo0 = wg << 2;

    float4 bv = *reinterpret_cast<const float4*>(bias + co);
    float acc[4][4];
    #pragma unroll
    for (int px = 0; px < 4; ++px) {
        acc[px][0] = bv.x; acc[px][1] = bv.y; acc[px][2] = bv.z; acc[px][3] = bv.w;
    }
    const int hb  = ho * STRIDE - 1;
    const int wb0 = wo0 * STRIDE - 1;

    for (int dy = 0; dy < 3; ++dy) {
        int hi = hb + dy;
        if ((unsigned)hi >= (unsigned)Hin) continue;
        const Tin* rowp = in + (long)(b * Hin + hi) * Win;
        float iv[NC];
        #pragma unroll
        for (int c = 0; c < NC; ++c) {
            int wi = wb0 + c;
            float v = 0.f;
            if ((unsigned)wi < (unsigned)Win) {
                if constexpr (std::is_same<Tin, float>::value) v = rowp[wi];
                else v = bu2f(rowp[wi]);
            }
            iv[c] = v;
        }
        #pragma unroll
        for (int dx = 0; dx < 3; ++dx) {
            const float* wp = wgt + (dy * 3 + dx) * COUT + co;
            float4 w = *reinterpret_cast<const float4*>(wp);
            #pragma unroll
            for (int px = 0; px < 4; ++px) {
                float v = iv[px * STRIDE + dx];
                acc[px][0] = fmaf(v, w.x, acc[px][0]); acc[px][1] = fmaf(v, w.y, acc[px][1]);
                acc[px][2] = fmaf(v, w.z, acc[px][2]); acc[px][3] = fmaf(v, w.w, acc[px][3]);
            }
        }
    }

    #pragma unroll
    for (int px = 0; px < 4; ++px) {
        ushort4 res;
        res.x = f2bu(lrelu(acc[px][0])); res.y = f2bu(lrelu(acc[px][1]));
        res.z = f2bu(lrelu(acc[px][2])); res.w = f2bu(lrelu(acc[px][3]));
        *reinterpret_cast<ushort4*>(out + ((long)(b * Ho + ho) * Wo + wo0 + px) * COUT + co) = res;
    }
}

template <int CIN, int COUT>
__global__ __launch_bounds__(256) void tconv3x3_t(
    const ushort_t* __restrict__ in, const float* __restrict__ wgt,
    const float* __restrict__ bias, const ushort_t* __restrict__ skip,
    ushort_t* __restrict__ out,
    int B, int Hin)
{
    const int Win = Hin;
    const int Ho = Hin * 2, Wo = Win * 2;
    constexpr int CoT = COUT >> 2;
    const int Wg = Win >> 1;
    int idx = blockIdx.x * 256 + threadIdx.x;
    int total = B * Hin * Wg * CoT;
    if (idx >= total) return;
    int cg = idx % CoT; int t = idx / CoT;
    int wg = t % Wg;    t /= Wg;
    int hi = t % Hin;   int b = t / Hin;
    int co = cg << 2;
    int wi = wg << 1;

    float4 bv = *reinterpret_cast<const float4*>(bias + co);
    float acc[2][4][4];
    #pragma unroll
    for (int oy = 0; oy < 2; ++oy)
        #pragma unroll
        for (int ox = 0; ox < 4; ++ox) {
            acc[oy][ox][0] = bv.x; acc[oy][ox][1] = bv.y;
            acc[oy][ox][2] = bv.z; acc[oy][ox][3] = bv.w;
        }

    const bool r1ok = (hi + 1) < Hin;
    const bool c1ok = (wi + 1) < Win;
    const bool c2ok = (wi + 2) < Win;

    constexpr int CG  = CIN / 4;
    constexpr int UNR = (CG >= 2) ? 2 : 1;
    #pragma unroll 1
    for (int cc = 0; cc < CG; cc += UNR) {
        float P[UNR][2][3][4];
        #pragma unroll
        for (int u = 0; u < UNR; ++u) {
            int ci = (cc + u) << 2;
            #pragma unroll
            for (int r = 0; r < 2; ++r) {
                #pragma unroll
                for (int c = 0; c < 3; ++c) {
                    bool ok = (r == 0 || r1ok) && (c == 0 || (c == 1 ? c1ok : c2ok));
                    if (ok) {
                        const ushort_t* ip = in + ((long)(b * Hin + hi + r) * Win + wi + c) * CIN + ci;
                        ushort4 v = *reinterpret_cast<const ushort4*>(ip);
                        P[u][r][c][0] = bu2f(v.x); P[u][r][c][1] = bu2f(v.y);
                        P[u][r][c][2] = bu2f(v.z); P[u][r][c][3] = bu2f(v.w);
                    } else {
                        P[u][r][c][0] = P[u][r][c][1] = P[u][r][c][2] = P[u][r][c][3] = 0.f;
                    }
                }
            }
        }
        #pragma unroll
        for (int u = 0; u < UNR; ++u) {
            int ci = (cc + u) << 2;
            #pragma unroll
            for (int dy = 0; dy < 3; ++dy) {
                #pragma unroll
                for (int dx = 0; dx < 3; ++dx) {
                    const int oy  = (dy == 1) ? 0 : 1;
                    const int ir  = (dy == 2) ? 1 : 0;
                    const int oxa = (dx == 1) ? 0 : 1;
                    const int ica = (dx == 2) ? 1 : 0;
                    const float* wp = wgt + ((dy * 3 + dx) * CIN + ci) * COUT + co;
                    float4 w0 = *reinterpret_cast<const float4*>(wp);
                    float4 w1 = *reinterpret_cast<const float4*>(wp + COUT);
                    float4 w2 = *reinterpret_cast<const float4*>(wp + 2 * COUT);
                    float4 w3 = *reinterpret_cast<const float4*>(wp + 3 * COUT);
                    #pragma unroll
                    for (int q = 0; q < 2; ++q) {
                        float* a = acc[oy][oxa + 2 * q];
                        const float* v = P[u][ir][ica + q];
                        a[0] = fmaf(v[0], w0.x, a[0]); a[1] = fmaf(v[0], w0.y, a[1]);
                        a[2] = fmaf(v[0], w0.z, a[2]); a[3] = fmaf(v[0], w0.w, a[3]);
                        a[0] = fmaf(v[1], w1.x, a[0]); a[1] = fmaf(v[1], w1.y, a[1]);
                        a[2] = fmaf(v[1], w1.z, a[2]); a[3] = fmaf(v[1], w1.w, a[3]);
                        a[0] = fmaf(v[2], w2.x, a[0]); a[1] = fmaf(v[2], w2.y, a[1]);
                        a[2] = fmaf(v[2], w2.z, a[2]); a[3] = fmaf(v[2], w2.w, a[3]);
                        a[0] = fmaf(v[3], w3.x, a[0]); a[1] = fmaf(v[3], w3.y, a[1]);
                        a[2] = fmaf(v[3], w3.z, a[2]); a[3] = fmaf(v[3], w3.w, a[3]);
                    }
                }
            }
        }
    }

    #pragma unroll
    for (int oy = 0; oy < 2; ++oy) {
        #pragma unroll
        for (int ox = 0; ox < 4; ++ox) {
            long o = ((long)(b * Ho + 2 * hi + oy) * Wo + 4 * wg + ox) * COUT + co;
            ushort4 sv = *reinterpret_cast<const ushort4*>(skip + o);
            ushort4 res;
            res.x = f2bu(lrelu(acc[oy][ox][0]) + bu2f(sv.x));
            res.y = f2bu(lrelu(acc[oy][ox][1]) + bu2f(sv.y));
            res.z = f2bu(lrelu(acc[oy][ox][2]) + bu2f(sv.z));
            res.w = f2bu(lrelu(acc[oy][ox][3]) + bu2f(sv.w));
            *reinterpret_cast<ushort4*>(out + o) = res;
        }
    }
}

__global__ __launch_bounds__(256) void dec0_out_mask_px4_kernel(
    const ushort_t* __restrict__ in,
    const float* __restrict__ w_dec, const float* __restrict__ b_dec,
    const float* __restrict__ w_out, const float* __restrict__ b_out,
    float* __restrict__ out, int B, int N)
{
    const int W4 = N >> 2;
    int idx = blockIdx.x * 256 + threadIdx.x;
    int total = B * N * W4;
    if (idx >= total) return;
    int wg  = idx % W4; int t = idx / W4;
    int row = t % N;    int b = t / N;
    int wo0 = wg << 2;

    float acc[4][16];
    #pragma unroll
    for (int px = 0; px < 4; ++px)
        #pragma unroll
        for (int c = 0; c < 16; ++c) acc[px][c] = b_dec[c];

    for (int dy = 0; dy < 3; ++dy) {
        int hi = row + dy - 1;
        if ((unsigned)hi >= (unsigned)N) continue;
        const ushort_t* rowp = in + ((long)(b * N + hi) * N) * 16;
        #pragma unroll 1
        for (int ci = 0; ci < 16; ci += 4) {
            float iv[6][4];
            #pragma unroll
            for (int c = 0; c < 6; ++c) {
                int wi = wo0 - 1 + c;
                if ((unsigned)wi < (unsigned)N) {
                    ushort4 v = *reinterpret_cast<const ushort4*>(rowp + (long)wi * 16 + ci);
                    iv[c][0] = bu2f(v.x); iv[c][1] = bu2f(v.y);
                    iv[c][2] = bu2f(v.z); iv[c][3] = bu2f(v.w);
                } else {
                    iv[c][0] = iv[c][1] = iv[c][2] = iv[c][3] = 0.f;
                }
            }
            #pragma unroll
            for (int dx = 0; dx < 3; ++dx) {
                #pragma unroll
                for (int k = 0; k < 4; ++k) {
                    const float* wr = w_dec + ((dy * 3 + dx) * 16 + ci + k) * 16;
                    float4 wa = *reinterpret_cast<const float4*>(wr);
                    float4 wb = *reinterpret_cast<const float4*>(wr + 4);
                    float4 wc = *reinterpret_cast<const float4*>(wr + 8);
                    float4 wd = *reinterpret_cast<const float4*>(wr + 12);
                    #pragma unroll
                    for (int px = 0; px < 4; ++px) {
                        float v = iv[px + dx][k];
                        acc[px][0]  = fmaf(v, wa.x, acc[px][0]);  acc[px][1]  = fmaf(v, wa.y, acc[px][1]);
                        acc[px][2]  = fmaf(v, wa.z, acc[px][2]);  acc[px][3]  = fmaf(v, wa.w, acc[px][3]);
                        acc[px][4]  = fmaf(v, wb.x, acc[px][4]);  acc[px][5]  = fmaf(v, wb.y, acc[px][5]);
                        acc[px][6]  = fmaf(v, wb.z, acc[px][6]);  acc[px][7]  = fmaf(v, wb.w, acc[px][7]);
                        acc[px][8]  = fmaf(v, wc.x, acc[px][8]);  acc[px][9]  = fmaf(v, wc.y, acc[px][9]);
                        acc[px][10] = fmaf(v, wc.z, acc[px][10]); acc[px][11] = fmaf(v, wc.w, acc[px][11]);
                        acc[px][12] = fmaf(v, wd.x, acc[px][12]); acc[px][13] = fmaf(v, wd.y, acc[px][13]);
                        acc[px][14] = fmaf(v, wd.z, acc[px][14]); acc[px][15] = fmaf(v, wd.w, acc[px][15]);
                    }
                }
            }
        }
    }

    float4 res;
    float* rp = &res.x;
    #pragma unroll
    for (int px = 0; px < 4; ++px) {
        float interim = b_out[0];
        #pragma unroll
        for (int c = 0; c < 16; ++c) interim = fmaf(lrelu(acc[px][c]), w_out[c], interim);
        int col = wo0 + px;
        float v;
        if (row < col) v = 0.f;
        else if (row == col) v = fmaxf(interim, 0.f) + log1pf(expf(-fabsf(interim)));
        else v = interim;
        rp[px] = v;
    }
    *reinterpret_cast<float4*>(out + ((long)(b * N + row) * N + wo0)) = res;
}

// ---------------------------------------------------------------------------
template <int CIN, int COUT, int STRIDE>
static void launch_mfma_conv(const ushort_t* in, const ushort_t* wB, const float* bias,
                             ushort_t* out, int Hin, hipStream_t stream)
{
    int Ho = Hin / STRIDE;
    long ntiles = (long)8 * Ho * (Ho >> 5) * (COUT >> 4);
    int blocks = (int)((ntiles + 3) / 4);
    hipLaunchKernelGGL((conv3x3_mfma<CIN, COUT, STRIDE>), dim3(blocks), dim3(256),
                       0, stream, in, wB, bias, out, Hin);
}

template <int CIN, int COUT>
static void launch_tconv(const ushort_t* in, const float* w, const float* bias,
                         const ushort_t* skip, ushort_t* out, int Hin, hipStream_t stream)
{
    int total = 8 * Hin * (Hin >> 1) * (COUT >> 2);
    hipLaunchKernelGGL((tconv3x3_t<CIN, COUT>), dim3((total + 255) / 256), dim3(256),
                       0, stream, in, w, bias, skip, out, 8, Hin);
}

extern "C" void kernel_launch(void* const* d_in, const int* in_sizes, int n_in,
                              void* d_out, int out_size, void* d_ws, size_t ws_size,
                              hipStream_t stream)
{
    const float* x      = (const float*)d_in[0];
    const float* w_enc1 = (const float*)d_in[1];  const float* b_enc1 = (const float*)d_in[2];
    const float* w_down1= (const float*)d_in[3];  const float* b_down1= (const float*)d_in[4];
    const float* w_enc2 = (const float*)d_in[5];  const float* b_enc2 = (const float*)d_in[6];
    const float* w_down2= (const float*)d_in[7];  const float* b_down2= (const float*)d_in[8];
    const float* w_enc3 = (const float*)d_in[9];  const float* b_enc3 = (const float*)d_in[10];
    const float* w_bn   = (const float*)d_in[11]; const float* b_bn   = (const float*)d_in[12];
    const float* w_up2  = (const float*)d_in[13]; const float* b_up2  = (const float*)d_in[14];
    const float* w_dec2 = (const float*)d_in[15]; const float* b_dec2 = (const float*)d_in[16];
    const float* w_up1  = (const float*)d_in[17]; const float* b_up1  = (const float*)d_in[18];
    const float* w_dec1 = (const float*)d_in[19]; const float* b_dec1 = (const float*)d_in[20];
    const float* w_up0  = (const float*)d_in[21]; const float* b_up0  = (const float*)d_in[22];
    const float* w_dec0 = (const float*)d_in[23]; const float* b_dec0 = (const float*)d_in[24];
    const float* w_out  = (const float*)d_in[25]; const float* b_out  = (const float*)d_in[26];

    // Workspace layout in bf16 elements. Total 88,080,384 elems = 168 MB.
    ushort_t* ws   = (ushort_t*)d_ws;
    ushort_t* E1   = ws;                 // [8,512,512,16] enc1, later up0 (in-place)
    ushort_t* T256 = E1   + 33554432;    // [8,256,256,32] down1, later up1
    ushort_t* E2   = T256 + 16777216;    // [8,256,256,32] enc2, later dec1
    ushort_t* T128 = E2   + 16777216;    // [8,128,128,64] down2, later up2
    ushort_t* E3   = T128 + 8388608;     // [8,128,128,64] enc3, later dec2
    ushort_t* T64  = E3   + 8388608;     // [8, 64, 64,128] bneck

    const size_t needed = 88080384ull * sizeof(ushort_t);
    if (ws_size < needed) {
        hipMemsetAsync(d_out, 0, (size_t)out_size * sizeof(float), stream);
        return;
    }

    // Repacked bf16 weights live in d_out scratch (overwritten by final kernel).
    // Layer order: down1, enc2, down2, enc3, bneck, dec2, dec1.
    // count = 9*KS*NG*512; offsets are prefix sums.
    ushort_t* wpk = (ushort_t*)d_out;
    RepackArgs ra;
    ra.d[0] = { w_down1,      0, 16,  32,  9216 };
    ra.d[1] = { w_enc2,    9216, 32,  32,  9216 };
    ra.d[2] = { w_down2,  18432, 32,  64, 18432 };
    ra.d[3] = { w_enc3,   36864, 64,  64, 36864 };
    ra.d[4] = { w_bn,     73728, 64, 128, 73728 };
    ra.d[5] = { w_dec2,  147456, 64,  64, 36864 };
    ra.d[6] = { w_dec1,  184320, 32,  32,  9216 };
    const int repack_total = 193536;
    hipLaunchKernelGGL(repack_weights, dim3((repack_total + 255) / 256), dim3(256), 0, stream,
                       ra, wpk, repack_total);

    // enc1 (Cin=1) stays VALU.
    {
        int total = 8 * 512 * 128 * 4;
        hipLaunchKernelGGL((conv3x3_t<float, 1, 16, 1>), dim3((total + 255) / 256), dim3(256),
                           0, stream, x, w_enc1, b_enc1, E1, 8, 512);
    }

    launch_mfma_conv<16,  32, 2>(E1,   wpk +      0, b_down1, T256, 512, stream); // down1
    launch_mfma_conv<32,  32, 1>(T256, wpk +   9216, b_enc2,  E2,   256, stream); // enc2
    launch_mfma_conv<32,  64, 2>(E2,   wpk +  18432, b_down2, T128, 256, stream); // down2
    launch_mfma_conv<64,  64, 1>(T128, wpk +  36864, b_enc3,  E3,   128, stream); // enc3
    launch_mfma_conv<64, 128, 2>(E3,   wpk +  73728, b_bn,    T64,  128, stream); // bneck
    launch_tconv<128, 64>(T64,  w_up2, b_up2, E3,   T128, 64,  stream);           // up2 = +enc3
    launch_mfma_conv<64,  64, 1>(T128, wpk + 147456, b_dec2,  E3,   128, stream); // dec2
    launch_tconv<64, 32>(E3,   w_up1, b_up1, E2,   T256, 128, stream);            // up1 = +enc2
    launch_mfma_conv<32,  32, 1>(T256, wpk + 184320, b_dec1,  E2,   256, stream); // dec1
    launch_tconv<32, 16>(E2,   w_up0, b_up0, E1,   E1,   256, stream);            // up0 = +enc1 (in-place)

    int total = 8 * 512 * 128;
    hipLaunchKernelGGL(dec0_out_mask_px4_kernel, dim3((total + 255) / 256), dim3(256), 0, stream,
                       E1, w_dec0, b_dec0, w_out, b_out, (float*)d_out, 8, 512);
}

// Round 12
// 875.579 us; speedup vs baseline: 7.4150x; 1.4903x over previous
//
#include <hip/hip_runtime.h>
#include <math.h>
#include <type_traits>

typedef unsigned short ushort_t;
typedef __attribute__((ext_vector_type(8))) short bf16x8;
typedef __attribute__((ext_vector_type(4))) float f32x4;

__device__ __forceinline__ float lrelu(float x) { return x >= 0.f ? x : 0.01f * x; }

// bf16 (raw ushort) <-> f32, RNE rounding.
__device__ __forceinline__ float bu2f(ushort_t u) {
    unsigned int x = ((unsigned int)u) << 16;
    float f; __builtin_memcpy(&f, &x, 4); return f;
}
__device__ __forceinline__ ushort_t f2bu(float f) {
    unsigned int x; __builtin_memcpy(&x, &f, 4);
    unsigned int r = (x + 0x7FFFu + ((x >> 16) & 1u)) >> 16;
    return (ushort_t)r;
}

// ---------------------------------------------------------------------------
// Weight repack: f32 [3,3,CIN,COUT] -> bf16 B-fragment order
// dst[(((tap*KS+kg)*NG+ng)*64+lane)*8+j] = w[tap][kg*32+8*(lane>>4)+j][ng*16+(lane&15)]
// (zero-padded where ci >= CIN). Runs every call; lands in d_out scratch.
// ---------------------------------------------------------------------------
struct RepackDesc { const float* src; int dst_off; int cin; int cout; int count; };
struct RepackArgs { RepackDesc d[10]; };

__global__ __launch_bounds__(256) void repack_weights(RepackArgs args, ushort_t* dst, int total)
{
    int idx = blockIdx.x * 256 + threadIdx.x;
    if (idx >= total) return;
    int l = 0, base = 0;
    #pragma unroll
    for (int i = 0; i < 10; ++i) {
        bool here = (idx >= base) && (idx < base + args.d[i].count);
        if (here) l = i;
        base += args.d[i].count;
    }
    base = 0;
    for (int i = 0; i < l; ++i) base += args.d[i].count;
    RepackDesc dsc = args.d[l];
    int local = idx - base;
    int j    = local & 7;
    int lane = (local >> 3) & 63;
    int rest = local >> 9;
    int NG = dsc.cout >> 4;
    int KS = (dsc.cin + 31) >> 5;
    int ng  = rest % NG; rest /= NG;
    int kg  = rest % KS;
    int tap = rest / KS;
    int ci = kg * 32 + ((lane >> 4) << 3) + j;
    int co = (ng << 4) + (lane & 15);
    float v = (ci < dsc.cin) ? dsc.src[((long)tap * dsc.cin + ci) * dsc.cout + co] : 0.f;
    dst[dsc.dst_off + local] = f2bu(v);
}

// ---------------------------------------------------------------------------
// Implicit-GEMM MFMA 3x3 conv, pad=1, stride 1/2, NHWC bf16 -> bf16.
// Wave tile: 32 output pixels (along w) x 16 couts. K-loop: 9 taps x CIN/32.
// A: row=lane&15 (pixel), k=8*(lane>>4)+j (cin)  [16B/lane]
// B: col=lane&15 (cout),  k=8*(lane>>4)+j        [16B/lane, repacked]
// D: col=lane&15 (cout),  row=4*(lane>>4)+reg (pixel)
// ---------------------------------------------------------------------------
template <int CIN, int COUT, int STRIDE>
__global__ __launch_bounds__(256) void conv3x3_mfma(
    const ushort_t* __restrict__ in, const ushort_t* __restrict__ wB,
    const float* __restrict__ bias, ushort_t* __restrict__ out, int Hin)
{
    const int Win = Hin, Ho = Hin / STRIDE, Wo = Win / STRIDE;
    constexpr int KS = (CIN + 31) >> 5;
    constexpr int NG = COUT >> 4;
    const int lane = threadIdx.x & 63;
    const int kq = lane >> 4, mn = lane & 15;
    const int wg = Wo >> 5;
    long tile = (long)blockIdx.x * 4 + (threadIdx.x >> 6);
    long ntiles = (long)8 * Ho * wg * NG;
    if (tile >= ntiles) return;
    int ng = (int)(tile % NG); long t2 = tile / NG;
    int wgi = (int)(t2 % wg); t2 /= wg;
    int ho = (int)(t2 % Ho); int b = (int)(t2 / Ho);
    int wo0 = wgi << 5;
    int co0 = ng << 4;

    f32x4 acc0 = {0.f, 0.f, 0.f, 0.f}, acc1 = {0.f, 0.f, 0.f, 0.f};
    const bf16x8 zero = {};

    const int px0 = wo0 + mn;        // A row -> output pixel (first 16)
    const int ciofs = kq << 3;       // cin offset within 32-slice

    #pragma unroll
    for (int dy = 0; dy < 3; ++dy) {
        int ih = ho * STRIDE + dy - 1;
        if ((unsigned)ih >= (unsigned)Hin) continue;
        const ushort_t* rowb = in + (long)(b * Hin + ih) * Win * CIN;
        #pragma unroll
        for (int dx = 0; dx < 3; ++dx) {
            int iw0 = px0 * STRIDE + dx - 1;
            int iw1 = iw0 + 16 * STRIDE;
            bool ok0 = (unsigned)iw0 < (unsigned)Win;
            bool ok1 = (unsigned)iw1 < (unsigned)Win;
            int c0 = ok0 ? iw0 : 0;
            int c1 = ok1 ? iw1 : 0;
            #pragma unroll
            for (int kg = 0; kg < KS; ++kg) {
                bf16x8 a0 = *reinterpret_cast<const bf16x8*>(rowb + (long)c0 * CIN + kg * 32 + ciofs);
                bf16x8 a1 = *reinterpret_cast<const bf16x8*>(rowb + (long)c1 * CIN + kg * 32 + ciofs);
                if (!ok0) a0 = zero;
                if (!ok1) a1 = zero;
                const ushort_t* wp = wB + (long)((((dy * 3 + dx) * KS + kg) * NG + ng) * 64 + lane) * 8;
                bf16x8 bw = *reinterpret_cast<const bf16x8*>(wp);
                acc0 = __builtin_amdgcn_mfma_f32_16x16x32_bf16(a0, bw, acc0, 0, 0, 0);
                acc1 = __builtin_amdgcn_mfma_f32_16x16x32_bf16(a1, bw, acc1, 0, 0, 0);
            }
        }
    }

    float bv = bias[co0 + mn];
    #pragma unroll
    for (int r = 0; r < 4; ++r) {
        int prow = (kq << 2) + r;     // pixel within 16-group
        long o0 = ((long)(b * Ho + ho) * Wo + wo0 + prow) * COUT + co0 + mn;
        out[o0]             = f2bu(lrelu(acc0[r] + bv));
        out[o0 + 16 * COUT] = f2bu(lrelu(acc1[r] + bv));
    }
}

// ---------------------------------------------------------------------------
// Implicit-GEMM MFMA transposed conv (k=3, lhs_dilation=2, pad (1,2)).
// Factorized by output parity: even ho -> y-tap {dy=1, ih=ho/2};
// odd ho -> {dy=0, ih=(ho-1)/2} + {dy=2, ih=(ho+1)/2 if < Hin}.
// Even wo -> x-tap {dx=1, wi=wo/2}; odd wo -> {dx=0}, {dx=2} (wi=(wo+dx-1)/2).
// Wave tile: one output row, one x-parity, 32 pixels (w-stride 2) x 16 couts.
// The 16 pixels of a fragment read CONSECUTIVE input columns -> same A pattern
// as conv3x3_mfma. Fused bias + lrelu + skip add (skip may alias out).
// ---------------------------------------------------------------------------
template <int CIN, int COUT>
__global__ __launch_bounds__(256) void tconv3x3_mfma(
    const ushort_t* __restrict__ in, const ushort_t* __restrict__ wB,
    const float* __restrict__ bias, const ushort_t* __restrict__ skip,
    ushort_t* __restrict__ out, int Hin)
{
    const int Win = Hin, Ho = Hin * 2, Wo = Win * 2;
    constexpr int KS = CIN >> 5;          // CIN in {32,64,128}
    constexpr int NG = COUT >> 4;
    const int lane = threadIdx.x & 63;
    const int kq = lane >> 4, mn = lane & 15;
    const int wg2 = Wo >> 6;              // 64 output cols per tile
    long tile = (long)blockIdx.x * 4 + (threadIdx.x >> 6);
    long ntiles = (long)8 * Ho * 2 * wg2 * NG;
    if (tile >= ntiles) return;
    int ng = (int)(tile % NG); long t2 = tile / NG;
    int wgi = (int)(t2 % wg2); t2 /= wg2;
    int p   = (int)(t2 & 1);   t2 >>= 1;  // x-parity
    int ho  = (int)(t2 % Ho);  int b = (int)(t2 / Ho);
    const int wbase = wgi << 6;           // first output col of tile (parity 0)
    const int wib   = wgi << 5;           // input col base
    const int co0   = ng << 4;

    f32x4 acc0 = {0.f, 0.f, 0.f, 0.f}, acc1 = {0.f, 0.f, 0.f, 0.f};
    const bf16x8 zero = {};
    const int ciofs = kq << 3;

    const int hoOdd = ho & 1;
    const int nyt = hoOdd ? ((((ho + 1) >> 1) < Hin) ? 2 : 1) : 1;
    const int nxt = p ? 2 : 1;

    for (int yt = 0; yt < nyt; ++yt) {
        int dy = hoOdd ? (yt == 0 ? 0 : 2) : 1;
        int ih = (ho + dy - 1) >> 1;
        const ushort_t* rowb = in + (long)(b * Hin + ih) * Win * CIN;
        for (int xt = 0; xt < nxt; ++xt) {
            int dx = p ? (xt == 0 ? 0 : 2) : 1;
            int xofs = (p + dx - 1) >> 1;       // 0 or 1
            int wi0 = wib + mn + xofs;
            int wi1 = wi0 + 16;
            bool ok0 = wi0 < Win;
            bool ok1 = wi1 < Win;
            int c0 = ok0 ? wi0 : 0;
            int c1 = ok1 ? wi1 : 0;
            #pragma unroll
            for (int kg = 0; kg < KS; ++kg) {
                bf16x8 a0 = *reinterpret_cast<const bf16x8*>(rowb + (long)c0 * CIN + kg * 32 + ciofs);
                bf16x8 a1 = *reinterpret_cast<const bf16x8*>(rowb + (long)c1 * CIN + kg * 32 + ciofs);
                if (!ok0) a0 = zero;
                if (!ok1) a1 = zero;
                const ushort_t* wp = wB + (long)((((dy * 3 + dx) * KS + kg) * NG + ng) * 64 + lane) * 8;
                bf16x8 bw = *reinterpret_cast<const bf16x8*>(wp);
                acc0 = __builtin_amdgcn_mfma_f32_16x16x32_bf16(a0, bw, acc0, 0, 0, 0);
                acc1 = __builtin_amdgcn_mfma_f32_16x16x32_bf16(a1, bw, acc1, 0, 0, 0);
            }
        }
    }

    float bv = bias[co0 + mn];
    #pragma unroll
    for (int r = 0; r < 4; ++r) {
        int prow = (kq << 2) + r;
        int woA = wbase + 2 * prow + p;
        long o0 = ((long)(b * Ho + ho) * Wo + woA) * COUT + co0 + mn;
        long o1 = o0 + 32 * COUT;           // pixel prow+16 (+32 output cols)
        out[o0] = f2bu(lrelu(acc0[r] + bv) + bu2f(skip[o0]));
        out[o1] = f2bu(lrelu(acc1[r] + bv) + bu2f(skip[o1]));
    }
}

// ---------------------------------------------------------------------------
// VALU kernels: enc1 (Cin=1) and fused dec0+1x1+mask.
// ---------------------------------------------------------------------------
template <typename Tin, int CIN, int COUT, int STRIDE>
__global__ __launch_bounds__(256) void conv3x3_t(
    const Tin* __restrict__ in, const float* __restrict__ wgt,
    const float* __restrict__ bias, ushort_t* __restrict__ out,
    int B, int Hin)
{
    const int Win = Hin;
    const int Ho = Hin / STRIDE, Wo = Win / STRIDE;
    constexpr int NC = 3 * STRIDE + 3;
    constexpr int CoT = COUT >> 2;
    const int Wo4 = Wo >> 2;
    int idx = blockIdx.x * 256 + threadIdx.x;
    int total = B * Ho * Wo4 * CoT;
    if (idx >= total) return;
    int cg = idx % CoT; int t = idx / CoT;
    int wg = t % Wo4;   t /= Wo4;
    int ho = t % Ho;    int b = t / Ho;
    int co = cg << 2;
    int wo0 = wg << 2;

    float4 bv = *reinterpret_cast<const float4*>(bias + co);
    float acc[4][4];
    #pragma unroll
    for (int px = 0; px < 4; ++px) {
        acc[px][0] = bv.x; acc[px][1] = bv.y; acc[px][2] = bv.z; acc[px][3] = bv.w;
    }
    const int hb  = ho * STRIDE - 1;
    const int wb0 = wo0 * STRIDE - 1;

    for (int dy = 0; dy < 3; ++dy) {
        int hi = hb + dy;
        if ((unsigned)hi >= (unsigned)Hin) continue;
        const Tin* rowp = in + (long)(b * Hin + hi) * Win;
        float iv[NC];
        #pragma unroll
        for (int c = 0; c < NC; ++c) {
            int wi = wb0 + c;
            float v = 0.f;
            if ((unsigned)wi < (unsigned)Win) {
                if constexpr (std::is_same<Tin, float>::value) v = rowp[wi];
                else v = bu2f(rowp[wi]);
            }
            iv[c] = v;
        }
        #pragma unroll
        for (int dx = 0; dx < 3; ++dx) {
            const float* wp = wgt + (dy * 3 + dx) * COUT + co;
            float4 w = *reinterpret_cast<const float4*>(wp);
            #pragma unroll
            for (int px = 0; px < 4; ++px) {
                float v = iv[px * STRIDE + dx];
                acc[px][0] = fmaf(v, w.x, acc[px][0]); acc[px][1] = fmaf(v, w.y, acc[px][1]);
                acc[px][2] = fmaf(v, w.z, acc[px][2]); acc[px][3] = fmaf(v, w.w, acc[px][3]);
            }
        }
    }

    #pragma unroll
    for (int px = 0; px < 4; ++px) {
        ushort4 res;
        res.x = f2bu(lrelu(acc[px][0])); res.y = f2bu(lrelu(acc[px][1]));
        res.z = f2bu(lrelu(acc[px][2])); res.w = f2bu(lrelu(acc[px][3]));
        *reinterpret_cast<ushort4*>(out + ((long)(b * Ho + ho) * Wo + wo0 + px) * COUT + co) = res;
    }
}

__global__ __launch_bounds__(256) void dec0_out_mask_px4_kernel(
    const ushort_t* __restrict__ in,
    const float* __restrict__ w_dec, const float* __restrict__ b_dec,
    const float* __restrict__ w_out, const float* __restrict__ b_out,
    float* __restrict__ out, int B, int N)
{
    const int W4 = N >> 2;
    int idx = blockIdx.x * 256 + threadIdx.x;
    int total = B * N * W4;
    if (idx >= total) return;
    int wg  = idx % W4; int t = idx / W4;
    int row = t % N;    int b = t / N;
    int wo0 = wg << 2;

    float acc[4][16];
    #pragma unroll
    for (int px = 0; px < 4; ++px)
        #pragma unroll
        for (int c = 0; c < 16; ++c) acc[px][c] = b_dec[c];

    for (int dy = 0; dy < 3; ++dy) {
        int hi = row + dy - 1;
        if ((unsigned)hi >= (unsigned)N) continue;
        const ushort_t* rowp = in + ((long)(b * N + hi) * N) * 16;
        #pragma unroll 1
        for (int ci = 0; ci < 16; ci += 4) {
            float iv[6][4];
            #pragma unroll
            for (int c = 0; c < 6; ++c) {
                int wi = wo0 - 1 + c;
                if ((unsigned)wi < (unsigned)N) {
                    ushort4 v = *reinterpret_cast<const ushort4*>(rowp + (long)wi * 16 + ci);
                    iv[c][0] = bu2f(v.x); iv[c][1] = bu2f(v.y);
                    iv[c][2] = bu2f(v.z); iv[c][3] = bu2f(v.w);
                } else {
                    iv[c][0] = iv[c][1] = iv[c][2] = iv[c][3] = 0.f;
                }
            }
            #pragma unroll
            for (int dx = 0; dx < 3; ++dx) {
                #pragma unroll
                for (int k = 0; k < 4; ++k) {
                    const float* wr = w_dec + ((dy * 3 + dx) * 16 + ci + k) * 16;
                    float4 wa = *reinterpret_cast<const float4*>(wr);
                    float4 wb = *reinterpret_cast<const float4*>(wr + 4);
                    float4 wc = *reinterpret_cast<const float4*>(wr + 8);
                    float4 wd = *reinterpret_cast<const float4*>(wr + 12);
                    #pragma unroll
                    for (int px = 0; px < 4; ++px) {
                        float v = iv[px + dx][k];
                        acc[px][0]  = fmaf(v, wa.x, acc[px][0]);  acc[px][1]  = fmaf(v, wa.y, acc[px][1]);
                        acc[px][2]  = fmaf(v, wa.z, acc[px][2]);  acc[px][3]  = fmaf(v, wa.w, acc[px][3]);
                        acc[px][4]  = fmaf(v, wb.x, acc[px][4]);  acc[px][5]  = fmaf(v, wb.y, acc[px][5]);
                        acc[px][6]  = fmaf(v, wb.z, acc[px][6]);  acc[px][7]  = fmaf(v, wb.w, acc[px][7]);
                        acc[px][8]  = fmaf(v, wc.x, acc[px][8]);  acc[px][9]  = fmaf(v, wc.y, acc[px][9]);
                        acc[px][10] = fmaf(v, wc.z, acc[px][10]); acc[px][11] = fmaf(v, wc.w, acc[px][11]);
                        acc[px][12] = fmaf(v, wd.x, acc[px][12]); acc[px][13] = fmaf(v, wd.y, acc[px][13]);
                        acc[px][14] = fmaf(v, wd.z, acc[px][14]); acc[px][15] = fmaf(v, wd.w, acc[px][15]);
                    }
                }
            }
        }
    }

    float4 res;
    float* rp = &res.x;
    #pragma unroll
    for (int px = 0; px < 4; ++px) {
        float interim = b_out[0];
        #pragma unroll
        for (int c = 0; c < 16; ++c) interim = fmaf(lrelu(acc[px][c]), w_out[c], interim);
        int col = wo0 + px;
        float v;
        if (row < col) v = 0.f;
        else if (row == col) v = fmaxf(interim, 0.f) + log1pf(expf(-fabsf(interim)));
        else v = interim;
        rp[px] = v;
    }
    *reinterpret_cast<float4*>(out + ((long)(b * N + row) * N + wo0)) = res;
}

// ---------------------------------------------------------------------------
template <int CIN, int COUT, int STRIDE>
static void launch_mfma_conv(const ushort_t* in, const ushort_t* wB, const float* bias,
                             ushort_t* out, int Hin, hipStream_t stream)
{
    int Ho = Hin / STRIDE;
    long ntiles = (long)8 * Ho * (Ho >> 5) * (COUT >> 4);
    int blocks = (int)((ntiles + 3) / 4);
    hipLaunchKernelGGL((conv3x3_mfma<CIN, COUT, STRIDE>), dim3(blocks), dim3(256),
                       0, stream, in, wB, bias, out, Hin);
}

template <int CIN, int COUT>
static void launch_mfma_tconv(const ushort_t* in, const ushort_t* wB, const float* bias,
                              const ushort_t* skip, ushort_t* out, int Hin, hipStream_t stream)
{
    int Ho = Hin * 2;
    long ntiles = (long)8 * Ho * 2 * (Ho >> 6) * (COUT >> 4);
    int blocks = (int)((ntiles + 3) / 4);
    hipLaunchKernelGGL((tconv3x3_mfma<CIN, COUT>), dim3(blocks), dim3(256),
                       0, stream, in, wB, bias, skip, out, Hin);
}

extern "C" void kernel_launch(void* const* d_in, const int* in_sizes, int n_in,
                              void* d_out, int out_size, void* d_ws, size_t ws_size,
                              hipStream_t stream)
{
    const float* x      = (const float*)d_in[0];
    const float* w_enc1 = (const float*)d_in[1];  const float* b_enc1 = (const float*)d_in[2];
    const float* w_down1= (const float*)d_in[3];  const float* b_down1= (const float*)d_in[4];
    const float* w_enc2 = (const float*)d_in[5];  const float* b_enc2 = (const float*)d_in[6];
    const float* w_down2= (const float*)d_in[7];  const float* b_down2= (const float*)d_in[8];
    const float* w_enc3 = (const float*)d_in[9];  const float* b_enc3 = (const float*)d_in[10];
    const float* w_bn   = (const float*)d_in[11]; const float* b_bn   = (const float*)d_in[12];
    const float* w_up2  = (const float*)d_in[13]; const float* b_up2  = (const float*)d_in[14];
    const float* w_dec2 = (const float*)d_in[15]; const float* b_dec2 = (const float*)d_in[16];
    const float* w_up1  = (const float*)d_in[17]; const float* b_up1  = (const float*)d_in[18];
    const float* w_dec1 = (const float*)d_in[19]; const float* b_dec1 = (const float*)d_in[20];
    const float* w_up0  = (const float*)d_in[21]; const float* b_up0  = (const float*)d_in[22];
    const float* w_dec0 = (const float*)d_in[23]; const float* b_dec0 = (const float*)d_in[24];
    const float* w_out  = (const float*)d_in[25]; const float* b_out  = (const float*)d_in[26];

    // Workspace layout in bf16 elements. Total 88,080,384 elems = 168 MB.
    ushort_t* ws   = (ushort_t*)d_ws;
    ushort_t* E1   = ws;                 // [8,512,512,16] enc1, later up0 (in-place)
    ushort_t* T256 = E1   + 33554432;    // [8,256,256,32] down1, later up1
    ushort_t* E2   = T256 + 16777216;    // [8,256,256,32] enc2, later dec1
    ushort_t* T128 = E2   + 16777216;    // [8,128,128,64] down2, later up2
    ushort_t* E3   = T128 + 8388608;     // [8,128,128,64] enc3, later dec2
    ushort_t* T64  = E3   + 8388608;     // [8, 64, 64,128] bneck

    const size_t needed = 88080384ull * sizeof(ushort_t);
    if (ws_size < needed) {
        hipMemsetAsync(d_out, 0, (size_t)out_size * sizeof(float), stream);
        return;
    }

    // Repacked bf16 weights live in d_out scratch (overwritten by final kernel).
    // Order: down1, enc2, down2, enc3, bn, dec2, dec1, up2, up1, up0.
    // count = 9*KS*NG*512; offsets are prefix sums. Total 290304 elems (580 KB).
    ushort_t* wpk = (ushort_t*)d_out;
    RepackArgs ra;
    ra.d[0] = { w_down1,      0,  16,  32,  9216 };
    ra.d[1] = { w_enc2,    9216,  32,  32,  9216 };
    ra.d[2] = { w_down2,  18432,  32,  64, 18432 };
    ra.d[3] = { w_enc3,   36864,  64,  64, 36864 };
    ra.d[4] = { w_bn,     73728,  64, 128, 73728 };
    ra.d[5] = { w_dec2,  147456,  64,  64, 36864 };
    ra.d[6] = { w_dec1,  184320,  32,  32,  9216 };
    ra.d[7] = { w_up2,   193536, 128,  64, 73728 };
    ra.d[8] = { w_up1,   267264,  64,  32, 18432 };
    ra.d[9] = { w_up0,   285696,  32,  16,  4608 };
    const int repack_total = 290304;
    hipLaunchKernelGGL(repack_weights, dim3((repack_total + 255) / 256), dim3(256), 0, stream,
                       ra, wpk, repack_total);

    // enc1 (Cin=1) stays VALU.
    {
        int total = 8 * 512 * 128 * 4;
        hipLaunchKernelGGL((conv3x3_t<float, 1, 16, 1>), dim3((total + 255) / 256), dim3(256),
                           0, stream, x, w_enc1, b_enc1, E1, 8, 512);
    }

    launch_mfma_conv<16,  32, 2>(E1,   wpk +      0, b_down1, T256, 512, stream); // down1
    launch_mfma_conv<32,  32, 1>(T256, wpk +   9216, b_enc2,  E2,   256, stream); // enc2
    launch_mfma_conv<32,  64, 2>(E2,   wpk +  18432, b_down2, T128, 256, stream); // down2
    launch_mfma_conv<64,  64, 1>(T128, wpk +  36864, b_enc3,  E3,   128, stream); // enc3
    launch_mfma_conv<64, 128, 2>(E3,   wpk +  73728, b_bn,    T64,  128, stream); // bneck
    launch_mfma_tconv<128, 64>(T64,  wpk + 193536, b_up2, E3, T128,  64, stream); // up2 = +enc3
    launch_mfma_conv<64,  64, 1>(T128, wpk + 147456, b_dec2,  E3,   128, stream); // dec2
    launch_mfma_tconv<64,  32>(E3,   wpk + 267264, b_up1, E2, T256, 128, stream); // up1 = +enc2
    launch_mfma_conv<32,  32, 1>(T256, wpk + 184320, b_dec1,  E2,   256, stream); // dec1
    launch_mfma_tconv<32,  16>(E2,   wpk + 285696, b_up0, E1, E1,   256, stream); // up0 = +enc1 (in-place)

    int total = 8 * 512 * 128;
    hipLaunchKernelGGL(dec0_out_mask_px4_kernel, dim3((total + 255) / 256), dim3(256), 0, stream,
                       E1, w_dec0, b_dec0, w_out, b_out, (float*)d_out, 8, 512);
}

// Round 13
// 770.462 us; speedup vs baseline: 8.4267x; 1.1364x over previous
//
#include <hip/hip_runtime.h>
#include <math.h>
#include <type_traits>

typedef unsigned short ushort_t;
typedef __attribute__((ext_vector_type(8))) short bf16x8;
typedef __attribute__((ext_vector_type(4))) float f32x4;

__device__ __forceinline__ float lrelu(float x) { return x >= 0.f ? x : 0.01f * x; }

// bf16 (raw ushort) <-> f32, RNE rounding.
__device__ __forceinline__ float bu2f(ushort_t u) {
    unsigned int x = ((unsigned int)u) << 16;
    float f; __builtin_memcpy(&f, &x, 4); return f;
}
__device__ __forceinline__ ushort_t f2bu(float f) {
    unsigned int x; __builtin_memcpy(&x, &f, 4);
    unsigned int r = (x + 0x7FFFu + ((x >> 16) & 1u)) >> 16;
    return (ushort_t)r;
}

// ---------------------------------------------------------------------------
// Weight repack: f32 [3,3,CIN,COUT] -> bf16 B-fragment order
// dst[(((tap*KS+kg)*NG+ng)*64+lane)*8+j] = w[tap][kg*32+8*(lane>>4)+j][ng*16+(lane&15)]
// (zero-padded where ci >= CIN). Runs every call; lands in workspace tail.
// ---------------------------------------------------------------------------
struct RepackDesc { const float* src; int dst_off; int cin; int cout; int count; };
struct RepackArgs { RepackDesc d[11]; };

__global__ __launch_bounds__(256) void repack_weights(RepackArgs args, ushort_t* dst, int total)
{
    int idx = blockIdx.x * 256 + threadIdx.x;
    if (idx >= total) return;
    int l = 0, base = 0;
    #pragma unroll
    for (int i = 0; i < 11; ++i) {
        bool here = (idx >= base) && (idx < base + args.d[i].count);
        if (here) l = i;
        base += args.d[i].count;
    }
    base = 0;
    for (int i = 0; i < l; ++i) base += args.d[i].count;
    RepackDesc dsc = args.d[l];
    int local = idx - base;
    int j    = local & 7;
    int lane = (local >> 3) & 63;
    int rest = local >> 9;
    int NG = dsc.cout >> 4;
    int KS = (dsc.cin + 31) >> 5;
    int ng  = rest % NG; rest /= NG;
    int kg  = rest % KS;
    int tap = rest / KS;
    int ci = kg * 32 + ((lane >> 4) << 3) + j;
    int co = (ng << 4) + (lane & 15);
    float v = (ci < dsc.cin) ? dsc.src[((long)tap * dsc.cin + ci) * dsc.cout + co] : 0.f;
    dst[dsc.dst_off + local] = f2bu(v);
}

// ---------------------------------------------------------------------------
// Implicit-GEMM MFMA 3x3 conv, pad=1, stride 1/2, NHWC bf16 -> bf16.
// Wave tile: 32 output pixels (along w) x 16 couts. K-loop: 9 taps x CIN/32.
// A: row=lane&15 (pixel), k=8*(lane>>4)+j (cin)  [16B/lane]
// B: col=lane&15 (cout),  k=8*(lane>>4)+j        [16B/lane, repacked]
// D: col=lane&15 (cout),  row=4*(lane>>4)+reg (pixel)
// ---------------------------------------------------------------------------
template <int CIN, int COUT, int STRIDE>
__global__ __launch_bounds__(256) void conv3x3_mfma(
    const ushort_t* __restrict__ in, const ushort_t* __restrict__ wB,
    const float* __restrict__ bias, ushort_t* __restrict__ out, int Hin)
{
    const int Win = Hin, Ho = Hin / STRIDE, Wo = Win / STRIDE;
    constexpr int KS = (CIN + 31) >> 5;
    constexpr int NG = COUT >> 4;
    const int lane = threadIdx.x & 63;
    const int kq = lane >> 4, mn = lane & 15;
    const int wg = Wo >> 5;
    long tile = (long)blockIdx.x * 4 + (threadIdx.x >> 6);
    long ntiles = (long)8 * Ho * wg * NG;
    if (tile >= ntiles) return;
    int ng = (int)(tile % NG); long t2 = tile / NG;
    int wgi = (int)(t2 % wg); t2 /= wg;
    int ho = (int)(t2 % Ho); int b = (int)(t2 / Ho);
    int wo0 = wgi << 5;
    int co0 = ng << 4;

    f32x4 acc0 = {0.f, 0.f, 0.f, 0.f}, acc1 = {0.f, 0.f, 0.f, 0.f};
    const bf16x8 zero = {};

    const int px0 = wo0 + mn;        // A row -> output pixel (first 16)
    const int ciofs = kq << 3;       // cin offset within 32-slice

    #pragma unroll
    for (int dy = 0; dy < 3; ++dy) {
        int ih = ho * STRIDE + dy - 1;
        if ((unsigned)ih >= (unsigned)Hin) continue;
        const ushort_t* rowb = in + (long)(b * Hin + ih) * Win * CIN;
        #pragma unroll
        for (int dx = 0; dx < 3; ++dx) {
            int iw0 = px0 * STRIDE + dx - 1;
            int iw1 = iw0 + 16 * STRIDE;
            bool ok0 = (unsigned)iw0 < (unsigned)Win;
            bool ok1 = (unsigned)iw1 < (unsigned)Win;
            int c0 = ok0 ? iw0 : 0;
            int c1 = ok1 ? iw1 : 0;
            #pragma unroll
            for (int kg = 0; kg < KS; ++kg) {
                bf16x8 a0 = *reinterpret_cast<const bf16x8*>(rowb + (long)c0 * CIN + kg * 32 + ciofs);
                bf16x8 a1 = *reinterpret_cast<const bf16x8*>(rowb + (long)c1 * CIN + kg * 32 + ciofs);
                if (!ok0) a0 = zero;
                if (!ok1) a1 = zero;
                const ushort_t* wp = wB + (long)((((dy * 3 + dx) * KS + kg) * NG + ng) * 64 + lane) * 8;
                bf16x8 bw = *reinterpret_cast<const bf16x8*>(wp);
                acc0 = __builtin_amdgcn_mfma_f32_16x16x32_bf16(a0, bw, acc0, 0, 0, 0);
                acc1 = __builtin_amdgcn_mfma_f32_16x16x32_bf16(a1, bw, acc1, 0, 0, 0);
            }
        }
    }

    float bv = bias[co0 + mn];
    #pragma unroll
    for (int r = 0; r < 4; ++r) {
        int prow = (kq << 2) + r;     // pixel within 16-group
        long o0 = ((long)(b * Ho + ho) * Wo + wo0 + prow) * COUT + co0 + mn;
        out[o0]             = f2bu(lrelu(acc0[r] + bv));
        out[o0 + 16 * COUT] = f2bu(lrelu(acc1[r] + bv));
    }
}

// ---------------------------------------------------------------------------
// Implicit-GEMM MFMA transposed conv (k=3, lhs_dilation=2, pad (1,2)).
// Factorized by output parity; wave tile = one output row, one x-parity,
// 32 pixels x 16 couts. Fused bias + lrelu + skip add (skip may alias out).
// ---------------------------------------------------------------------------
template <int CIN, int COUT>
__global__ __launch_bounds__(256) void tconv3x3_mfma(
    const ushort_t* __restrict__ in, const ushort_t* __restrict__ wB,
    const float* __restrict__ bias, const ushort_t* __restrict__ skip,
    ushort_t* __restrict__ out, int Hin)
{
    const int Win = Hin, Ho = Hin * 2, Wo = Win * 2;
    constexpr int KS = CIN >> 5;          // CIN in {32,64,128}
    constexpr int NG = COUT >> 4;
    const int lane = threadIdx.x & 63;
    const int kq = lane >> 4, mn = lane & 15;
    const int wg2 = Wo >> 6;              // 64 output cols per tile
    long tile = (long)blockIdx.x * 4 + (threadIdx.x >> 6);
    long ntiles = (long)8 * Ho * 2 * wg2 * NG;
    if (tile >= ntiles) return;
    int ng = (int)(tile % NG); long t2 = tile / NG;
    int wgi = (int)(t2 % wg2); t2 /= wg2;
    int p   = (int)(t2 & 1);   t2 >>= 1;  // x-parity
    int ho  = (int)(t2 % Ho);  int b = (int)(t2 / Ho);
    const int wbase = wgi << 6;
    const int wib   = wgi << 5;
    const int co0   = ng << 4;

    f32x4 acc0 = {0.f, 0.f, 0.f, 0.f}, acc1 = {0.f, 0.f, 0.f, 0.f};
    const bf16x8 zero = {};
    const int ciofs = kq << 3;

    const int hoOdd = ho & 1;
    const int nyt = hoOdd ? ((((ho + 1) >> 1) < Hin) ? 2 : 1) : 1;
    const int nxt = p ? 2 : 1;

    for (int yt = 0; yt < nyt; ++yt) {
        int dy = hoOdd ? (yt == 0 ? 0 : 2) : 1;
        int ih = (ho + dy - 1) >> 1;
        const ushort_t* rowb = in + (long)(b * Hin + ih) * Win * CIN;
        for (int xt = 0; xt < nxt; ++xt) {
            int dx = p ? (xt == 0 ? 0 : 2) : 1;
            int xofs = (p + dx - 1) >> 1;       // 0 or 1
            int wi0 = wib + mn + xofs;
            int wi1 = wi0 + 16;
            bool ok0 = wi0 < Win;
            bool ok1 = wi1 < Win;
            int c0 = ok0 ? wi0 : 0;
            int c1 = ok1 ? wi1 : 0;
            #pragma unroll
            for (int kg = 0; kg < KS; ++kg) {
                bf16x8 a0 = *reinterpret_cast<const bf16x8*>(rowb + (long)c0 * CIN + kg * 32 + ciofs);
                bf16x8 a1 = *reinterpret_cast<const bf16x8*>(rowb + (long)c1 * CIN + kg * 32 + ciofs);
                if (!ok0) a0 = zero;
                if (!ok1) a1 = zero;
                const ushort_t* wp = wB + (long)((((dy * 3 + dx) * KS + kg) * NG + ng) * 64 + lane) * 8;
                bf16x8 bw = *reinterpret_cast<const bf16x8*>(wp);
                acc0 = __builtin_amdgcn_mfma_f32_16x16x32_bf16(a0, bw, acc0, 0, 0, 0);
                acc1 = __builtin_amdgcn_mfma_f32_16x16x32_bf16(a1, bw, acc1, 0, 0, 0);
            }
        }
    }

    float bv = bias[co0 + mn];
    #pragma unroll
    for (int r = 0; r < 4; ++r) {
        int prow = (kq << 2) + r;
        int woA = wbase + 2 * prow + p;
        long o0 = ((long)(b * Ho + ho) * Wo + woA) * COUT + co0 + mn;
        long o1 = o0 + 32 * COUT;           // pixel prow+16 (+32 output cols)
        out[o0] = f2bu(lrelu(acc0[r] + bv) + bu2f(skip[o0]));
        out[o1] = f2bu(lrelu(acc1[r] + bv) + bu2f(skip[o1]));
    }
}

// ---------------------------------------------------------------------------
// Fused final stage, MFMA: dec0 (3x3 conv 16->16 via implicit GEMM) + 1x1
// conv 16->1 (cross-lane butterfly reduce over couts) + triangular mask +
// softplus on diagonal. Reads bf16 up0, writes f32 d_out.
// D-fragment: lane holds cout=mn for pixels 4*kq+r (+16). The 1x1 is
// sum over cout -> __shfl_xor over masks 1,2,4,8 (within 16-lane group).
// ---------------------------------------------------------------------------
__global__ __launch_bounds__(256) void dec0_mfma_mask(
    const ushort_t* __restrict__ in, const ushort_t* __restrict__ wB,
    const float* __restrict__ b_dec, const float* __restrict__ w_out,
    const float* __restrict__ b_out, float* __restrict__ out, int Hin)
{
    const int Win = Hin, Ho = Hin, Wo = Hin;   // CIN=COUT=16, stride 1
    const int lane = threadIdx.x & 63;
    const int kq = lane >> 4, mn = lane & 15;
    const int wg = Wo >> 5;
    long tile = (long)blockIdx.x * 4 + (threadIdx.x >> 6);
    long ntiles = (long)8 * Ho * wg;           // NG = 1
    if (tile >= ntiles) return;
    int wgi = (int)(tile % wg); long t2 = tile / wg;
    int ho = (int)(t2 % Ho); int b = (int)(t2 / Ho);
    int wo0 = wgi << 5;

    f32x4 acc0 = {0.f, 0.f, 0.f, 0.f}, acc1 = {0.f, 0.f, 0.f, 0.f};
    const bf16x8 zero = {};
    const int px0 = wo0 + mn;
    const int ciofs = kq << 3;   // kq>=2 reads next pixel's channels; B is zero there

    #pragma unroll
    for (int dy = 0; dy < 3; ++dy) {
        int ih = ho + dy - 1;
        if ((unsigned)ih >= (unsigned)Hin) continue;
        const ushort_t* rowb = in + (long)(b * Hin + ih) * Win * 16;
        #pragma unroll
        for (int dx = 0; dx < 3; ++dx) {
            int iw0 = px0 + dx - 1;
            int iw1 = iw0 + 16;
            bool ok0 = (unsigned)iw0 < (unsigned)Win;
            bool ok1 = (unsigned)iw1 < (unsigned)Win;
            int c0 = ok0 ? iw0 : 0;
            int c1 = ok1 ? iw1 : 0;
            bf16x8 a0 = *reinterpret_cast<const bf16x8*>(rowb + (long)c0 * 16 + ciofs);
            bf16x8 a1 = *reinterpret_cast<const bf16x8*>(rowb + (long)c1 * 16 + ciofs);
            if (!ok0) a0 = zero;
            if (!ok1) a1 = zero;
            const ushort_t* wp = wB + (long)((dy * 3 + dx) * 64 + lane) * 8;
            bf16x8 bw = *reinterpret_cast<const bf16x8*>(wp);
            acc0 = __builtin_amdgcn_mfma_f32_16x16x32_bf16(a0, bw, acc0, 0, 0, 0);
            acc1 = __builtin_amdgcn_mfma_f32_16x16x32_bf16(a1, bw, acc1, 0, 0, 0);
        }
    }

    float bv = b_dec[mn];
    float wv = w_out[mn];
    float bo = b_out[0];
    float4 r0, r1;
    float* p0 = &r0.x;
    float* p1 = &r1.x;
    #pragma unroll
    for (int r = 0; r < 4; ++r) {
        float v0 = lrelu(acc0[r] + bv) * wv;
        float v1 = lrelu(acc1[r] + bv) * wv;
        #pragma unroll
        for (int m = 1; m < 16; m <<= 1) {
            v0 += __shfl_xor(v0, m);
            v1 += __shfl_xor(v1, m);
        }
        p0[r] = v0 + bo;
        p1[r] = v1 + bo;
    }

    if (mn == 0) {
        int colb0 = wo0 + (kq << 2);
        #pragma unroll
        for (int r = 0; r < 4; ++r) {
            int c0 = colb0 + r, c1 = c0 + 16;
            float v0 = p0[r], v1 = p1[r];
            if (ho < c0) v0 = 0.f;
            else if (ho == c0) v0 = fmaxf(v0, 0.f) + log1pf(expf(-fabsf(v0)));
            if (ho < c1) v1 = 0.f;
            else if (ho == c1) v1 = fmaxf(v1, 0.f) + log1pf(expf(-fabsf(v1)));
            p0[r] = v0; p1[r] = v1;
        }
        long rowo = (long)(b * Ho + ho) * Wo;
        *reinterpret_cast<float4*>(out + rowo + colb0)      = r0;
        *reinterpret_cast<float4*>(out + rowo + colb0 + 16) = r1;
    }
}

// ---------------------------------------------------------------------------
// VALU kernel: enc1 (Cin=1).
// ---------------------------------------------------------------------------
template <typename Tin, int CIN, int COUT, int STRIDE>
__global__ __launch_bounds__(256) void conv3x3_t(
    const Tin* __restrict__ in, const float* __restrict__ wgt,
    const float* __restrict__ bias, ushort_t* __restrict__ out,
    int B, int Hin)
{
    const int Win = Hin;
    const int Ho = Hin / STRIDE, Wo = Win / STRIDE;
    constexpr int NC = 3 * STRIDE + 3;
    constexpr int CoT = COUT >> 2;
    const int Wo4 = Wo >> 2;
    int idx = blockIdx.x * 256 + threadIdx.x;
    int total = B * Ho * Wo4 * CoT;
    if (idx >= total) return;
    int cg = idx % CoT; int t = idx / CoT;
    int wg = t % Wo4;   t /= Wo4;
    int ho = t % Ho;    int b = t / Ho;
    int co = cg << 2;
    int wo0 = wg << 2;

    float4 bv = *reinterpret_cast<const float4*>(bias + co);
    float acc[4][4];
    #pragma unroll
    for (int px = 0; px < 4; ++px) {
        acc[px][0] = bv.x; acc[px][1] = bv.y; acc[px][2] = bv.z; acc[px][3] = bv.w;
    }
    const int hb  = ho * STRIDE - 1;
    const int wb0 = wo0 * STRIDE - 1;

    for (int dy = 0; dy < 3; ++dy) {
        int hi = hb + dy;
        if ((unsigned)hi >= (unsigned)Hin) continue;
        const Tin* rowp = in + (long)(b * Hin + hi) * Win;
        float iv[NC];
        #pragma unroll
        for (int c = 0; c < NC; ++c) {
            int wi = wb0 + c;
            float v = 0.f;
            if ((unsigned)wi < (unsigned)Win) {
                if constexpr (std::is_same<Tin, float>::value) v = rowp[wi];
                else v = bu2f(rowp[wi]);
            }
            iv[c] = v;
        }
        #pragma unroll
        for (int dx = 0; dx < 3; ++dx) {
            const float* wp = wgt + (dy * 3 + dx) * COUT + co;
            float4 w = *reinterpret_cast<const float4*>(wp);
            #pragma unroll
            for (int px = 0; px < 4; ++px) {
                float v = iv[px * STRIDE + dx];
                acc[px][0] = fmaf(v, w.x, acc[px][0]); acc[px][1] = fmaf(v, w.y, acc[px][1]);
                acc[px][2] = fmaf(v, w.z, acc[px][2]); acc[px][3] = fmaf(v, w.w, acc[px][3]);
            }
        }
    }

    #pragma unroll
    for (int px = 0; px < 4; ++px) {
        ushort4 res;
        res.x = f2bu(lrelu(acc[px][0])); res.y = f2bu(lrelu(acc[px][1]));
        res.z = f2bu(lrelu(acc[px][2])); res.w = f2bu(lrelu(acc[px][3]));
        *reinterpret_cast<ushort4*>(out + ((long)(b * Ho + ho) * Wo + wo0 + px) * COUT + co) = res;
    }
}

// ---------------------------------------------------------------------------
template <int CIN, int COUT, int STRIDE>
static void launch_mfma_conv(const ushort_t* in, const ushort_t* wB, const float* bias,
                             ushort_t* out, int Hin, hipStream_t stream)
{
    int Ho = Hin / STRIDE;
    long ntiles = (long)8 * Ho * (Ho >> 5) * (COUT >> 4);
    int blocks = (int)((ntiles + 3) / 4);
    hipLaunchKernelGGL((conv3x3_mfma<CIN, COUT, STRIDE>), dim3(blocks), dim3(256),
                       0, stream, in, wB, bias, out, Hin);
}

template <int CIN, int COUT>
static void launch_mfma_tconv(const ushort_t* in, const ushort_t* wB, const float* bias,
                              const ushort_t* skip, ushort_t* out, int Hin, hipStream_t stream)
{
    int Ho = Hin * 2;
    long ntiles = (long)8 * Ho * 2 * (Ho >> 6) * (COUT >> 4);
    int blocks = (int)((ntiles + 3) / 4);
    hipLaunchKernelGGL((tconv3x3_mfma<CIN, COUT>), dim3(blocks), dim3(256),
                       0, stream, in, wB, bias, skip, out, Hin);
}

extern "C" void kernel_launch(void* const* d_in, const int* in_sizes, int n_in,
                              void* d_out, int out_size, void* d_ws, size_t ws_size,
                              hipStream_t stream)
{
    const float* x      = (const float*)d_in[0];
    const float* w_enc1 = (const float*)d_in[1];  const float* b_enc1 = (const float*)d_in[2];
    const float* w_down1= (const float*)d_in[3];  const float* b_down1= (const float*)d_in[4];
    const float* w_enc2 = (const float*)d_in[5];  const float* b_enc2 = (const float*)d_in[6];
    const float* w_down2= (const float*)d_in[7];  const float* b_down2= (const float*)d_in[8];
    const float* w_enc3 = (const float*)d_in[9];  const float* b_enc3 = (const float*)d_in[10];
    const float* w_bn   = (const float*)d_in[11]; const float* b_bn   = (const float*)d_in[12];
    const float* w_up2  = (const float*)d_in[13]; const float* b_up2  = (const float*)d_in[14];
    const float* w_dec2 = (const float*)d_in[15]; const float* b_dec2 = (const float*)d_in[16];
    const float* w_up1  = (const float*)d_in[17]; const float* b_up1  = (const float*)d_in[18];
    const float* w_dec1 = (const float*)d_in[19]; const float* b_dec1 = (const float*)d_in[20];
    const float* w_up0  = (const float*)d_in[21]; const float* b_up0  = (const float*)d_in[22];
    const float* w_dec0 = (const float*)d_in[23]; const float* b_dec0 = (const float*)d_in[24];
    const float* w_out  = (const float*)d_in[25]; const float* b_out  = (const float*)d_in[26];

    // Workspace layout in bf16 elements:
    //   intermediates: 88,080,384 elems (168 MB)
    //   repacked weights (wpk): 294,912 elems (576 KB) at the tail
    ushort_t* ws   = (ushort_t*)d_ws;
    ushort_t* E1   = ws;                 // [8,512,512,16] enc1, later up0 (in-place)
    ushort_t* T256 = E1   + 33554432;    // [8,256,256,32] down1, later up1
    ushort_t* E2   = T256 + 16777216;    // [8,256,256,32] enc2, later dec1
    ushort_t* T128 = E2   + 16777216;    // [8,128,128,64] down2, later up2
    ushort_t* E3   = T128 + 8388608;     // [8,128,128,64] enc3, later dec2
    ushort_t* T64  = E3   + 8388608;     // [8, 64, 64,128] bneck
    ushort_t* wpk  = T64  + 4194304;     // repacked weights (294,912 elems)

    const int repack_total = 294912;
    const size_t needed = (88080384ull + (size_t)repack_total) * sizeof(ushort_t);
    if (ws_size < needed) {
        hipMemsetAsync(d_out, 0, (size_t)out_size * sizeof(float), stream);
        return;
    }

    // Order: down1, enc2, down2, enc3, bn, dec2, dec1, up2, up1, up0, dec0.
    // count = 9*KS*NG*512; offsets are prefix sums.
    RepackArgs ra;
    ra.d[0]  = { w_down1,      0,  16,  32,  9216 };
    ra.d[1]  = { w_enc2,    9216,  32,  32,  9216 };
    ra.d[2]  = { w_down2,  18432,  32,  64, 18432 };
    ra.d[3]  = { w_enc3,   36864,  64,  64, 36864 };
    ra.d[4]  = { w_bn,     73728,  64, 128, 73728 };
    ra.d[5]  = { w_dec2,  147456,  64,  64, 36864 };
    ra.d[6]  = { w_dec1,  184320,  32,  32,  9216 };
    ra.d[7]  = { w_up2,   193536, 128,  64, 73728 };
    ra.d[8]  = { w_up1,   267264,  64,  32, 18432 };
    ra.d[9]  = { w_up0,   285696,  32,  16,  4608 };
    ra.d[10] = { w_dec0,  290304,  16,  16,  4608 };
    hipLaunchKernelGGL(repack_weights, dim3((repack_total + 255) / 256), dim3(256), 0, stream,
                       ra, wpk, repack_total);

    // enc1 (Cin=1) stays VALU.
    {
        int total = 8 * 512 * 128 * 4;
        hipLaunchKernelGGL((conv3x3_t<float, 1, 16, 1>), dim3((total + 255) / 256), dim3(256),
                           0, stream, x, w_enc1, b_enc1, E1, 8, 512);
    }

    launch_mfma_conv<16,  32, 2>(E1,   wpk +      0, b_down1, T256, 512, stream); // down1
    launch_mfma_conv<32,  32, 1>(T256, wpk +   9216, b_enc2,  E2,   256, stream); // enc2
    launch_mfma_conv<32,  64, 2>(E2,   wpk +  18432, b_down2, T128, 256, stream); // down2
    launch_mfma_conv<64,  64, 1>(T128, wpk +  36864, b_enc3,  E3,   128, stream); // enc3
    launch_mfma_conv<64, 128, 2>(E3,   wpk +  73728, b_bn,    T64,  128, stream); // bneck
    launch_mfma_tconv<128, 64>(T64,  wpk + 193536, b_up2, E3, T128,  64, stream); // up2 = +enc3
    launch_mfma_conv<64,  64, 1>(T128, wpk + 147456, b_dec2,  E3,   128, stream); // dec2
    launch_mfma_tconv<64,  32>(E3,   wpk + 267264, b_up1, E2, T256, 128, stream); // up1 = +enc2
    launch_mfma_conv<32,  32, 1>(T256, wpk + 184320, b_dec1,  E2,   256, stream); // dec1
    launch_mfma_tconv<32,  16>(E2,   wpk + 285696, b_up0, E1, E1,   256, stream); // up0 = +enc1 (in-place)

    // Fused dec0 + 1x1 + mask/softplus (MFMA).
    {
        long ntiles = (long)8 * 512 * 16;      // 8*Ho*(Wo>>5), NG=1
        int blocks = (int)((ntiles + 3) / 4);
        hipLaunchKernelGGL(dec0_mfma_mask, dim3(blocks), dim3(256), 0, stream,
                           E1, wpk + 290304, b_dec0, w_out, b_out, (float*)d_out, 512);
    }
}

// Round 14
// 591.656 us; speedup vs baseline: 10.9734x; 1.3022x over previous
//
#include <hip/hip_runtime.h>
#include <math.h>
#include <type_traits>

typedef unsigned short ushort_t;
typedef __attribute__((ext_vector_type(8))) short bf16x8;
typedef __attribute__((ext_vector_type(4))) float f32x4;

__device__ __forceinline__ float lrelu(float x) { return x >= 0.f ? x : 0.01f * x; }

// bf16 (raw ushort) <-> f32, RNE rounding.
__device__ __forceinline__ float bu2f(ushort_t u) {
    unsigned int x = ((unsigned int)u) << 16;
    float f; __builtin_memcpy(&f, &x, 4); return f;
}
__device__ __forceinline__ ushort_t f2bu(float f) {
    unsigned int x; __builtin_memcpy(&x, &f, 4);
    unsigned int r = (x + 0x7FFFu + ((x >> 16) & 1u)) >> 16;
    return (ushort_t)r;
}

// ---------------------------------------------------------------------------
// Weight repack: f32 [3,3,CIN,COUT] -> bf16 B-fragment order
// dst[(((tap*KS+kg)*NG+ng)*64+lane)*8+j] = w[tap][kg*32+8*(lane>>4)+j][ng*16+(lane&15)]
// (zero-padded where ci >= CIN). Runs every call; lands in workspace tail.
// ---------------------------------------------------------------------------
struct RepackDesc { const float* src; int dst_off; int cin; int cout; int count; };
struct RepackArgs { RepackDesc d[11]; };

__global__ __launch_bounds__(256) void repack_weights(RepackArgs args, ushort_t* dst, int total)
{
    int idx = blockIdx.x * 256 + threadIdx.x;
    if (idx >= total) return;
    int l = 0, base = 0;
    #pragma unroll
    for (int i = 0; i < 11; ++i) {
        bool here = (idx >= base) && (idx < base + args.d[i].count);
        if (here) l = i;
        base += args.d[i].count;
    }
    base = 0;
    for (int i = 0; i < l; ++i) base += args.d[i].count;
    RepackDesc dsc = args.d[l];
    int local = idx - base;
    int j    = local & 7;
    int lane = (local >> 3) & 63;
    int rest = local >> 9;
    int NG = dsc.cout >> 4;
    int KS = (dsc.cin + 31) >> 5;
    int ng  = rest % NG; rest /= NG;
    int kg  = rest % KS;
    int tap = rest / KS;
    int ci = kg * 32 + ((lane >> 4) << 3) + j;
    int co = (ng << 4) + (lane & 15);
    float v = (ci < dsc.cin) ? dsc.src[((long)tap * dsc.cin + ci) * dsc.cout + co] : 0.f;
    dst[dsc.dst_off + local] = f2bu(v);
}

// ---------------------------------------------------------------------------
// Implicit-GEMM MFMA 3x3 conv, pad=1, stride 1/2, NHWC bf16 -> bf16.
// Wave tile: 32 output pixels (along w) x MG*16 couts. K: 9 taps x CIN/32.
// A: row=lane&15 (pixel), k=8*(lane>>4)+j (cin); B repacked; D: col=mn=cout,
// row=4*kq+reg=pixel. MG cout-groups share the A fragments (2x MFMA:load).
// ---------------------------------------------------------------------------
template <int CIN, int COUT, int STRIDE, int MG>
__global__ __launch_bounds__(256) void conv3x3_mfma(
    const ushort_t* __restrict__ in, const ushort_t* __restrict__ wB,
    const float* __restrict__ bias, ushort_t* __restrict__ out, int Hin)
{
    const int Win = Hin, Ho = Hin / STRIDE, Wo = Win / STRIDE;
    constexpr int KS = (CIN + 31) >> 5;
    constexpr int NG = COUT >> 4;
    constexpr int NGW = NG / MG;
    const int lane = threadIdx.x & 63;
    const int kq = lane >> 4, mn = lane & 15;
    const int wg = Wo >> 5;
    long tile = (long)blockIdx.x * 4 + (threadIdx.x >> 6);
    long ntiles = (long)8 * Ho * wg * NGW;
    if (tile >= ntiles) return;
    int ngw = (int)(tile % NGW); long t2 = tile / NGW;
    int wgi = (int)(t2 % wg); t2 /= wg;
    int ho = (int)(t2 % Ho); int b = (int)(t2 / Ho);
    int wo0 = wgi << 5;
    int ngb = ngw * MG;

    f32x4 acc[MG][2];
    #pragma unroll
    for (int m = 0; m < MG; ++m) {
        acc[m][0] = {0.f, 0.f, 0.f, 0.f};
        acc[m][1] = {0.f, 0.f, 0.f, 0.f};
    }
    const bf16x8 zero = {};

    const int px0 = wo0 + mn;        // A row -> output pixel (first 16)
    const int ciofs = kq << 3;       // cin offset within 32-slice

    #pragma unroll
    for (int dy = 0; dy < 3; ++dy) {
        int ih = ho * STRIDE + dy - 1;
        if ((unsigned)ih >= (unsigned)Hin) continue;
        const ushort_t* rowb = in + (long)(b * Hin + ih) * Win * CIN;
        #pragma unroll
        for (int dx = 0; dx < 3; ++dx) {
            int iw0 = px0 * STRIDE + dx - 1;
            int iw1 = iw0 + 16 * STRIDE;
            bool ok0 = (unsigned)iw0 < (unsigned)Win;
            bool ok1 = (unsigned)iw1 < (unsigned)Win;
            int c0 = ok0 ? iw0 : 0;
            int c1 = ok1 ? iw1 : 0;
            #pragma unroll
            for (int kg = 0; kg < KS; ++kg) {
                bf16x8 a0 = *reinterpret_cast<const bf16x8*>(rowb + (long)c0 * CIN + kg * 32 + ciofs);
                bf16x8 a1 = *reinterpret_cast<const bf16x8*>(rowb + (long)c1 * CIN + kg * 32 + ciofs);
                if (!ok0) a0 = zero;
                if (!ok1) a1 = zero;
                const ushort_t* wp0 = wB + (long)((((dy * 3 + dx) * KS + kg) * NG + ngb) * 64 + lane) * 8;
                #pragma unroll
                for (int m = 0; m < MG; ++m) {
                    bf16x8 bw = *reinterpret_cast<const bf16x8*>(wp0 + (long)m * 512);
                    acc[m][0] = __builtin_amdgcn_mfma_f32_16x16x32_bf16(a0, bw, acc[m][0], 0, 0, 0);
                    acc[m][1] = __builtin_amdgcn_mfma_f32_16x16x32_bf16(a1, bw, acc[m][1], 0, 0, 0);
                }
            }
        }
    }

    #pragma unroll
    for (int m = 0; m < MG; ++m) {
        int co0 = (ngb + m) << 4;
        float bv = bias[co0 + mn];
        #pragma unroll
        for (int r = 0; r < 4; ++r) {
            int prow = (kq << 2) + r;
            long o0 = ((long)(b * Ho + ho) * Wo + wo0 + prow) * COUT + co0 + mn;
            out[o0]             = f2bu(lrelu(acc[m][0][r] + bv));
            out[o0 + 16 * COUT] = f2bu(lrelu(acc[m][1][r] + bv));
        }
    }
}

// ---------------------------------------------------------------------------
// Implicit-GEMM MFMA transposed conv (k=3, lhs_dilation=2, pad (1,2)).
// Factorized by output parity; wave tile = one output row, one x-parity,
// PF*16 pixels x MG*16 couts. Fused bias + lrelu + skip add (may alias out).
// ---------------------------------------------------------------------------
template <int CIN, int COUT, int MG, int PF>
__global__ __launch_bounds__(256) void tconv3x3_mfma(
    const ushort_t* __restrict__ in, const ushort_t* __restrict__ wB,
    const float* __restrict__ bias, const ushort_t* __restrict__ skip,
    ushort_t* __restrict__ out, int Hin)
{
    const int Win = Hin, Ho = Hin * 2, Wo = Win * 2;
    constexpr int KS = CIN >> 5;          // CIN in {32,64,128}
    constexpr int NG = COUT >> 4;
    constexpr int NGW = NG / MG;
    const int lane = threadIdx.x & 63;
    const int kq = lane >> 4, mn = lane & 15;
    const int wgn = Wo / (32 * PF);       // tiles per row (per parity)
    long tile = (long)blockIdx.x * 4 + (threadIdx.x >> 6);
    long ntiles = (long)8 * Ho * 2 * wgn * NGW;
    if (tile >= ntiles) return;
    int ngw = (int)(tile % NGW); long t2 = tile / NGW;
    int wgi = (int)(t2 % wgn); t2 /= wgn;
    int p   = (int)(t2 & 1);   t2 >>= 1;  // x-parity
    int ho  = (int)(t2 % Ho);  int b = (int)(t2 / Ho);
    const int wbase = wgi * (32 * PF);
    const int wib   = wgi * (16 * PF);
    const int ngb   = ngw * MG;

    f32x4 acc[MG][PF];
    #pragma unroll
    for (int m = 0; m < MG; ++m)
        #pragma unroll
        for (int f = 0; f < PF; ++f) acc[m][f] = {0.f, 0.f, 0.f, 0.f};
    const bf16x8 zero = {};
    const int ciofs = kq << 3;

    const int hoOdd = ho & 1;
    const int nyt = hoOdd ? ((((ho + 1) >> 1) < Hin) ? 2 : 1) : 1;
    const int nxt = p ? 2 : 1;

    for (int yt = 0; yt < nyt; ++yt) {
        int dy = hoOdd ? (yt == 0 ? 0 : 2) : 1;
        int ih = (ho + dy - 1) >> 1;
        const ushort_t* rowb = in + (long)(b * Hin + ih) * Win * CIN;
        for (int xt = 0; xt < nxt; ++xt) {
            int dx = p ? (xt == 0 ? 0 : 2) : 1;
            int xofs = (p + dx - 1) >> 1;       // 0 or 1
            #pragma unroll
            for (int kg = 0; kg < KS; ++kg) {
                bf16x8 a[PF];
                #pragma unroll
                for (int f = 0; f < PF; ++f) {
                    int wi = wib + f * 16 + mn + xofs;
                    bool ok = wi < Win;
                    int c = ok ? wi : 0;
                    a[f] = *reinterpret_cast<const bf16x8*>(rowb + (long)c * CIN + kg * 32 + ciofs);
                    if (!ok) a[f] = zero;
                }
                const ushort_t* wp0 = wB + (long)((((dy * 3 + dx) * KS + kg) * NG + ngb) * 64 + lane) * 8;
                #pragma unroll
                for (int m = 0; m < MG; ++m) {
                    bf16x8 bw = *reinterpret_cast<const bf16x8*>(wp0 + (long)m * 512);
                    #pragma unroll
                    for (int f = 0; f < PF; ++f)
                        acc[m][f] = __builtin_amdgcn_mfma_f32_16x16x32_bf16(a[f], bw, acc[m][f], 0, 0, 0);
                }
            }
        }
    }

    #pragma unroll
    for (int m = 0; m < MG; ++m) {
        int co0 = (ngb + m) << 4;
        float bv = bias[co0 + mn];
        #pragma unroll
        for (int f = 0; f < PF; ++f) {
            #pragma unroll
            for (int r = 0; r < 4; ++r) {
                int prow = f * 16 + (kq << 2) + r;
                int woA = wbase + 2 * prow + p;
                long o = ((long)(b * Ho + ho) * Wo + woA) * COUT + co0 + mn;
                out[o] = f2bu(lrelu(acc[m][f][r] + bv) + bu2f(skip[o]));
            }
        }
    }
}

// ---------------------------------------------------------------------------
// Fused final stage, MFMA: dec0 (3x3 conv 16->16) + 1x1 conv 16->1
// (cross-lane butterfly over couts) + mask + softplus. bf16 in, f32 out.
// ---------------------------------------------------------------------------
__global__ __launch_bounds__(256) void dec0_mfma_mask(
    const ushort_t* __restrict__ in, const ushort_t* __restrict__ wB,
    const float* __restrict__ b_dec, const float* __restrict__ w_out,
    const float* __restrict__ b_out, float* __restrict__ out, int Hin)
{
    const int Win = Hin, Ho = Hin, Wo = Hin;   // CIN=COUT=16, stride 1
    const int lane = threadIdx.x & 63;
    const int kq = lane >> 4, mn = lane & 15;
    const int wg = Wo >> 5;
    long tile = (long)blockIdx.x * 4 + (threadIdx.x >> 6);
    long ntiles = (long)8 * Ho * wg;           // NG = 1
    if (tile >= ntiles) return;
    int wgi = (int)(tile % wg); long t2 = tile / wg;
    int ho = (int)(t2 % Ho); int b = (int)(t2 / Ho);
    int wo0 = wgi << 5;

    f32x4 acc0 = {0.f, 0.f, 0.f, 0.f}, acc1 = {0.f, 0.f, 0.f, 0.f};
    const bf16x8 zero = {};
    const int px0 = wo0 + mn;
    const int ciofs = kq << 3;   // kq>=2 reads next pixel's channels; B is zero there

    #pragma unroll
    for (int dy = 0; dy < 3; ++dy) {
        int ih = ho + dy - 1;
        if ((unsigned)ih >= (unsigned)Hin) continue;
        const ushort_t* rowb = in + (long)(b * Hin + ih) * Win * 16;
        #pragma unroll
        for (int dx = 0; dx < 3; ++dx) {
            int iw0 = px0 + dx - 1;
            int iw1 = iw0 + 16;
            bool ok0 = (unsigned)iw0 < (unsigned)Win;
            bool ok1 = (unsigned)iw1 < (unsigned)Win;
            int c0 = ok0 ? iw0 : 0;
            int c1 = ok1 ? iw1 : 0;
            bf16x8 a0 = *reinterpret_cast<const bf16x8*>(rowb + (long)c0 * 16 + ciofs);
            bf16x8 a1 = *reinterpret_cast<const bf16x8*>(rowb + (long)c1 * 16 + ciofs);
            if (!ok0) a0 = zero;
            if (!ok1) a1 = zero;
            const ushort_t* wp = wB + (long)((dy * 3 + dx) * 64 + lane) * 8;
            bf16x8 bw = *reinterpret_cast<const bf16x8*>(wp);
            acc0 = __builtin_amdgcn_mfma_f32_16x16x32_bf16(a0, bw, acc0, 0, 0, 0);
            acc1 = __builtin_amdgcn_mfma_f32_16x16x32_bf16(a1, bw, acc1, 0, 0, 0);
        }
    }

    float bv = b_dec[mn];
    float wv = w_out[mn];
    float bo = b_out[0];
    float4 r0, r1;
    float* p0 = &r0.x;
    float* p1 = &r1.x;
    #pragma unroll
    for (int r = 0; r < 4; ++r) {
        float v0 = lrelu(acc0[r] + bv) * wv;
        float v1 = lrelu(acc1[r] + bv) * wv;
        #pragma unroll
        for (int m = 1; m < 16; m <<= 1) {
            v0 += __shfl_xor(v0, m);
            v1 += __shfl_xor(v1, m);
        }
        p0[r] = v0 + bo;
        p1[r] = v1 + bo;
    }

    if (mn == 0) {
        int colb0 = wo0 + (kq << 2);
        #pragma unroll
        for (int r = 0; r < 4; ++r) {
            int c0 = colb0 + r, c1 = c0 + 16;
            float v0 = p0[r], v1 = p1[r];
            if (ho < c0) v0 = 0.f;
            else if (ho == c0) v0 = fmaxf(v0, 0.f) + log1pf(expf(-fabsf(v0)));
            if (ho < c1) v1 = 0.f;
            else if (ho == c1) v1 = fmaxf(v1, 0.f) + log1pf(expf(-fabsf(v1)));
            p0[r] = v0; p1[r] = v1;
        }
        long rowo = (long)(b * Ho + ho) * Wo;
        *reinterpret_cast<float4*>(out + rowo + colb0)      = r0;
        *reinterpret_cast<float4*>(out + rowo + colb0 + 16) = r1;
    }
}

// ---------------------------------------------------------------------------
// VALU kernel: enc1 (Cin=1).
// ---------------------------------------------------------------------------
template <typename Tin, int CIN, int COUT, int STRIDE>
__global__ __launch_bounds__(256) void conv3x3_t(
    const Tin* __restrict__ in, const float* __restrict__ wgt,
    const float* __restrict__ bias, ushort_t* __restrict__ out,
    int B, int Hin)
{
    const int Win = Hin;
    const int Ho = Hin / STRIDE, Wo = Win / STRIDE;
    constexpr int NC = 3 * STRIDE + 3;
    constexpr int CoT = COUT >> 2;
    const int Wo4 = Wo >> 2;
    int idx = blockIdx.x * 256 + threadIdx.x;
    int total = B * Ho * Wo4 * CoT;
    if (idx >= total) return;
    int cg = idx % CoT; int t = idx / CoT;
    int wg = t % Wo4;   t /= Wo4;
    int ho = t % Ho;    int b = t / Ho;
    int co = cg << 2;
    int wo0 = wg << 2;

    float4 bv = *reinterpret_cast<const float4*>(bias + co);
    float acc[4][4];
    #pragma unroll
    for (int px = 0; px < 4; ++px) {
        acc[px][0] = bv.x; acc[px][1] = bv.y; acc[px][2] = bv.z; acc[px][3] = bv.w;
    }
    const int hb  = ho * STRIDE - 1;
    const int wb0 = wo0 * STRIDE - 1;

    for (int dy = 0; dy < 3; ++dy) {
        int hi = hb + dy;
        if ((unsigned)hi >= (unsigned)Hin) continue;
        const Tin* rowp = in + (long)(b * Hin + hi) * Win;
        float iv[NC];
        #pragma unroll
        for (int c = 0; c < NC; ++c) {
            int wi = wb0 + c;
            float v = 0.f;
            if ((unsigned)wi < (unsigned)Win) {
                if constexpr (std::is_same<Tin, float>::value) v = rowp[wi];
                else v = bu2f(rowp[wi]);
            }
            iv[c] = v;
        }
        #pragma unroll
        for (int dx = 0; dx < 3; ++dx) {
            const float* wp = wgt + (dy * 3 + dx) * COUT + co;
            float4 w = *reinterpret_cast<const float4*>(wp);
            #pragma unroll
            for (int px = 0; px < 4; ++px) {
                float v = iv[px * STRIDE + dx];
                acc[px][0] = fmaf(v, w.x, acc[px][0]); acc[px][1] = fmaf(v, w.y, acc[px][1]);
                acc[px][2] = fmaf(v, w.z, acc[px][2]); acc[px][3] = fmaf(v, w.w, acc[px][3]);
            }
        }
    }

    #pragma unroll
    for (int px = 0; px < 4; ++px) {
        ushort4 res;
        res.x = f2bu(lrelu(acc[px][0])); res.y = f2bu(lrelu(acc[px][1]));
        res.z = f2bu(lrelu(acc[px][2])); res.w = f2bu(lrelu(acc[px][3]));
        *reinterpret_cast<ushort4*>(out + ((long)(b * Ho + ho) * Wo + wo0 + px) * COUT + co) = res;
    }
}

// ---------------------------------------------------------------------------
template <int CIN, int COUT, int STRIDE, int MG>
static void launch_mfma_conv(const ushort_t* in, const ushort_t* wB, const float* bias,
                             ushort_t* out, int Hin, hipStream_t stream)
{
    int Ho = Hin / STRIDE;
    long ntiles = (long)8 * Ho * (Ho >> 5) * ((COUT >> 4) / MG);
    int blocks = (int)((ntiles + 3) / 4);
    hipLaunchKernelGGL((conv3x3_mfma<CIN, COUT, STRIDE, MG>), dim3(blocks), dim3(256),
                       0, stream, in, wB, bias, out, Hin);
}

template <int CIN, int COUT, int MG, int PF>
static void launch_mfma_tconv(const ushort_t* in, const ushort_t* wB, const float* bias,
                              const ushort_t* skip, ushort_t* out, int Hin, hipStream_t stream)
{
    int Ho = Hin * 2;
    long ntiles = (long)8 * Ho * 2 * (Ho / (32 * PF)) * ((COUT >> 4) / MG);
    int blocks = (int)((ntiles + 3) / 4);
    hipLaunchKernelGGL((tconv3x3_mfma<CIN, COUT, MG, PF>), dim3(blocks), dim3(256),
                       0, stream, in, wB, bias, skip, out, Hin);
}

extern "C" void kernel_launch(void* const* d_in, const int* in_sizes, int n_in,
                              void* d_out, int out_size, void* d_ws, size_t ws_size,
                              hipStream_t stream)
{
    const float* x      = (const float*)d_in[0];
    const float* w_enc1 = (const float*)d_in[1];  const float* b_enc1 = (const float*)d_in[2];
    const float* w_down1= (const float*)d_in[3];  const float* b_down1= (const float*)d_in[4];
    const float* w_enc2 = (const float*)d_in[5];  const float* b_enc2 = (const float*)d_in[6];
    const float* w_down2= (const float*)d_in[7];  const float* b_down2= (const float*)d_in[8];
    const float* w_enc3 = (const float*)d_in[9];  const float* b_enc3 = (const float*)d_in[10];
    const float* w_bn   = (const float*)d_in[11]; const float* b_bn   = (const float*)d_in[12];
    const float* w_up2  = (const float*)d_in[13]; const float* b_up2  = (const float*)d_in[14];
    const float* w_dec2 = (const float*)d_in[15]; const float* b_dec2 = (const float*)d_in[16];
    const float* w_up1  = (const float*)d_in[17]; const float* b_up1  = (const float*)d_in[18];
    const float* w_dec1 = (const float*)d_in[19]; const float* b_dec1 = (const float*)d_in[20];
    const float* w_up0  = (const float*)d_in[21]; const float* b_up0  = (const float*)d_in[22];
    const float* w_dec0 = (const float*)d_in[23]; const float* b_dec0 = (const float*)d_in[24];
    const float* w_out  = (const float*)d_in[25]; const float* b_out  = (const float*)d_in[26];

    // Workspace layout in bf16 elements:
    //   intermediates: 88,080,384 elems (168 MB)
    //   repacked weights (wpk): 294,912 elems (576 KB) at the tail
    ushort_t* ws   = (ushort_t*)d_ws;
    ushort_t* E1   = ws;                 // [8,512,512,16] enc1, later up0 (in-place)
    ushort_t* T256 = E1   + 33554432;    // [8,256,256,32] down1, later up1
    ushort_t* E2   = T256 + 16777216;    // [8,256,256,32] enc2, later dec1
    ushort_t* T128 = E2   + 16777216;    // [8,128,128,64] down2, later up2
    ushort_t* E3   = T128 + 8388608;     // [8,128,128,64] enc3, later dec2
    ushort_t* T64  = E3   + 8388608;     // [8, 64, 64,128] bneck
    ushort_t* wpk  = T64  + 4194304;     // repacked weights (294,912 elems)

    const int repack_total = 294912;
    const size_t needed = (88080384ull + (size_t)repack_total) * sizeof(ushort_t);
    if (ws_size < needed) {
        hipMemsetAsync(d_out, 0, (size_t)out_size * sizeof(float), stream);
        return;
    }

    // Order: down1, enc2, down2, enc3, bn, dec2, dec1, up2, up1, up0, dec0.
    // count = 9*KS*NG*512; offsets are prefix sums.
    RepackArgs ra;
    ra.d[0]  = { w_down1,      0,  16,  32,  9216 };
    ra.d[1]  = { w_enc2,    9216,  32,  32,  9216 };
    ra.d[2]  = { w_down2,  18432,  32,  64, 18432 };
    ra.d[3]  = { w_enc3,   36864,  64,  64, 36864 };
    ra.d[4]  = { w_bn,     73728,  64, 128, 73728 };
    ra.d[5]  = { w_dec2,  147456,  64,  64, 36864 };
    ra.d[6]  = { w_dec1,  184320,  32,  32,  9216 };
    ra.d[7]  = { w_up2,   193536, 128,  64, 73728 };
    ra.d[8]  = { w_up1,   267264,  64,  32, 18432 };
    ra.d[9]  = { w_up0,   285696,  32,  16,  4608 };
    ra.d[10] = { w_dec0,  290304,  16,  16,  4608 };
    hipLaunchKernelGGL(repack_weights, dim3((repack_total + 255) / 256), dim3(256), 0, stream,
                       ra, wpk, repack_total);

    // enc1 (Cin=1) stays VALU.
    {
        int total = 8 * 512 * 128 * 4;
        hipLaunchKernelGGL((conv3x3_t<float, 1, 16, 1>), dim3((total + 255) / 256), dim3(256),
                           0, stream, x, w_enc1, b_enc1, E1, 8, 512);
    }

    launch_mfma_conv<16,  32, 2, 2>(E1,   wpk +      0, b_down1, T256, 512, stream); // down1
    launch_mfma_conv<32,  32, 1, 2>(T256, wpk +   9216, b_enc2,  E2,   256, stream); // enc2
    launch_mfma_conv<32,  64, 2, 2>(E2,   wpk +  18432, b_down2, T128, 256, stream); // down2
    launch_mfma_conv<64,  64, 1, 2>(T128, wpk +  36864, b_enc3,  E3,   128, stream); // enc3
    launch_mfma_conv<64, 128, 2, 2>(E3,   wpk +  73728, b_bn,    T64,  128, stream); // bneck
    launch_mfma_tconv<128, 64, 2, 2>(T64,  wpk + 193536, b_up2, E3, T128,  64, stream); // up2 = +enc3
    launch_mfma_conv<64,  64, 1, 2>(T128, wpk + 147456, b_dec2,  E3,   128, stream); // dec2
    launch_mfma_tconv<64,  32, 2, 2>(E3,   wpk + 267264, b_up1, E2, T256, 128, stream); // up1 = +enc2
    launch_mfma_conv<32,  32, 1, 2>(T256, wpk + 184320, b_dec1,  E2,   256, stream); // dec1
    launch_mfma_tconv<32,  16, 1, 4>(E2,   wpk + 285696, b_up0, E1, E1,   256, stream); // up0 = +enc1 (in-place)

    // Fused dec0 + 1x1 + mask/softplus (MFMA).
    {
        long ntiles = (long)8 * 512 * 16;      // 8*Ho*(Wo>>5), NG=1
        int blocks = (int)((ntiles + 3) / 4);
        hipLaunchKernelGGL(dec0_mfma_mask, dim3(blocks), dim3(256), 0, stream,
                           E1, wpk + 290304, b_dec0, w_out, b_out, (float*)d_out, 512);
    }
}